// Round 9
// baseline (321.648 us; speedup 1.0000x reference)
//
#include <hip/hip_runtime.h>
#include <hip/hip_bf16.h>
#include <math.h>

#define NEG_SLOPE 0.2f
#define ECLAMP 30.0f
#define HCLAMP 1.0e4f

#define BSHIFT 8
#define BR 256
#define NBMAX 1024
#define CHUNK 2048

typedef short v8s __attribute__((ext_vector_type(8)));
typedef float v4f __attribute__((ext_vector_type(4)));
typedef unsigned long long ull;

__device__ __forceinline__ float bf2f(__hip_bfloat16 v) { return __bfloat162float(v); }
__device__ __forceinline__ __hip_bfloat16 f2bf(float v) { return __float2bfloat16(v); }
__device__ __forceinline__ float sane(float v)   { return fminf(fmaxf(v, -HCLAMP), HCLAMP); }
__device__ __forceinline__ float eclampf(float v){ return fminf(fmaxf(v, -ECLAMP), ECLAMP); }

__device__ __forceinline__ float ldany(int isf32, const void* p, int i) {
    return isf32 ? ((const float*)p)[i] : bf2f(((const __hip_bfloat16*)p)[i]);
}
__device__ __forceinline__ int ldidx(int is64, const void* p, long long i) {
    return is64 ? (int)((const long long*)p)[i] : ((const int*)p)[i];
}
__device__ __forceinline__ v8s ld8(const __hip_bfloat16* p) { return *(const v8s*)p; }

// leaky_relu + clamp + exp
__device__ __forceinline__ float ewgt(float e) {
    e = e > 0.f ? e : NEG_SLOPE * e;
    return __expf(eclampf(e));
}

__device__ __forceinline__ float bflo(unsigned v) { return __uint_as_float(v << 16); }
__device__ __forceinline__ float bfhi(unsigned v) { return __uint_as_float(v & 0xffff0000u); }
__device__ __forceinline__ unsigned packbf(float a, float b) {
    __hip_bfloat16 x = f2bf(a), y = f2bf(b);
    return (unsigned)(*(unsigned short*)&x) | ((unsigned)(*(unsigned short*)&y) << 16);
}

// ---------- inline dtype probes (deterministic, per block; contributions from tid<256) ----------
__device__ __forceinline__ int probe_isf32(const unsigned* xw, int nw_safe, int tid, int* cnt) {
    if (tid == 0) cnt[0] = 0;
    __syncthreads();
    if (tid < 256) {
        unsigned w = xw[(unsigned)(tid * 9973) % (unsigned)nw_safe];
        unsigned lo = w & 0xffffu;
        unsigned e = (lo >> 7) & 0xffu;
        if (lo != 0u && (e < 90u || e > 160u)) atomicAdd(&cnt[0], 1);
    }
    __syncthreads();
    int r = (2 * cnt[0] > 256) ? 1 : 0;
    __syncthreads();   // allow LDS reuse
    return r;
}
__device__ __forceinline__ int probe_is64(const unsigned* ew, int tid, int* cnt) {
    if (tid == 0) cnt[0] = 0;
    __syncthreads();
    if (tid < 256) {
        if (ew[2 * tid + 1] == 0u) atomicAdd(&cnt[0], 1);
    }
    __syncthreads();
    int r = (cnt[0] >= 200) ? 1 : 0;
    __syncthreads();
    return r;
}

// ================= MERGED: chunk histogram (blocks < gch)  ∪  layer-0 transform =================
__global__ __launch_bounds__(256) void k1_chist_l0(
    const void* __restrict__ ei, const void* __restrict__ x,
    const void* W0, const void* sW0, const void* as0, const void* ad0,
    const void* b0, const void* sb0,
    int N, int E, int NB, int gch,
    int* __restrict__ hist,
    __hip_bfloat16* __restrict__ h0, __hip_bfloat16* __restrict__ skip0,
    float* __restrict__ ssrc, float* __restrict__ sdst) {
    __shared__ __align__(16) char smraw[52224];
    int tid = threadIdx.x;

    if ((int)blockIdx.x < gch) {
        // ---------- chist part ----------
        int f = probe_is64((const unsigned*)ei, tid, (int*)smraw);
        int* h = (int*)smraw;
        for (int i = tid; i < NB; i += 256) h[i] = 0;
        __syncthreads();
        long long c0 = (long long)blockIdx.x * CHUNK;
        long long c1 = c0 + CHUNK;
        if (c1 > E) c1 = E;
        for (long long i = c0 + tid; i < c1; i += 256) {
            unsigned d = (unsigned)ldidx(f, ei, (long long)E + i);
            if (d < (unsigned)N) atomicAdd(&h[d >> BSHIFT], 1);
        }
        __syncthreads();
        long long base = (long long)blockIdx.x * NB;
        for (int i = tid; i < NB; i += 256) hist[base + i] = h[i];
        return;
    }

    // ---------- layer-0 transform part ----------
    int f = probe_isf32((const unsigned*)x, N * 64, tid, (int*)smraw);
    __hip_bfloat16* xs  = (__hip_bfloat16*)smraw;
    __hip_bfloat16* wt0 = xs + 8704;
    __hip_bfloat16* wts = xs + 17408;
    int tile = ((int)blockIdx.x - gch) * 64;

    for (int i = tid * 4; i < 8192; i += 1024) {
        int r = i >> 7, k = i & 127;
        __hip_bfloat16 a0[4], a1[4];
#pragma unroll
        for (int u = 0; u < 4; u++) {
            a0[u] = f2bf(ldany(f, W0,  (k + u) * 64 + r));
            a1[u] = f2bf(ldany(f, sW0, (k + u) * 64 + r));
        }
        *(uint2*)&wt0[r * 136 + k] = *(uint2*)a0;
        *(uint2*)&wts[r * 136 + k] = *(uint2*)a1;
    }
    for (int i = tid * 4; i < 8192; i += 1024) {
        int r = i >> 7, k = i & 127;
        int g = tile + r; if (g >= N) g = N - 1;
        uint2* dx = (uint2*)&xs[r * 136 + k];
        if (f) {
            float4 v = *(const float4*)((const float*)x + (size_t)g * 128 + k);
            uint2 o; o.x = packbf(v.x, v.y); o.y = packbf(v.z, v.w);
            *dx = o;
        } else {
            *dx = *(const uint2*)((const __hip_bfloat16*)x + (size_t)g * 128 + k);
        }
    }
    __syncthreads();

    int lane = tid & 63, w = tid >> 6;
    int n16 = lane & 15, quad = lane >> 4;
    v4f zf = {0.f, 0.f, 0.f, 0.f};
    v4f acc_h[4], acc_s[4];
#pragma unroll
    for (int t = 0; t < 4; t++) { acc_h[t] = zf; acc_s[t] = zf; }

    int arow = (w << 4) + n16;
#pragma unroll
    for (int s = 0; s < 4; s++) {
        v8s a = ld8(&xs[arow * 136 + s * 32 + (quad << 3)]);
#pragma unroll
        for (int t = 0; t < 4; t++) {
            v8s bh = ld8(&wt0[(t * 16 + n16) * 136 + s * 32 + (quad << 3)]);
            acc_h[t] = __builtin_amdgcn_mfma_f32_16x16x32_bf16(a, bh, acc_h[t], 0, 0, 0);
            v8s bs = ld8(&wts[(t * 16 + n16) * 136 + s * 32 + (quad << 3)]);
            acc_s[t] = __builtin_amdgcn_mfma_f32_16x16x32_bf16(a, bs, acc_s[t], 0, 0, 0);
        }
    }

    int mbase = tile + (w << 4) + (quad << 2);
    float ps[4] = {0, 0, 0, 0}, pd[4] = {0, 0, 0, 0};
#pragma unroll
    for (int t = 0; t < 4; t++) {
        int ch = t * 16 + n16;
        float av = ldany(f, as0, ch);
        float dv = ldany(f, ad0, ch);
        float bv = ldany(f, b0, ch) + ldany(f, sb0, ch);
#pragma unroll
        for (int r = 0; r < 4; r++) {
            float hv = sane(acc_h[t][r]);
            float sv = sane(acc_s[t][r] + bv);
            int node = mbase + r;
            if (node < N) {
                h0[(size_t)node * 64 + ch] = f2bf(hv);
                skip0[(size_t)node * 64 + ch] = f2bf(sv);
            }
            ps[r] += hv * av;
            pd[r] += hv * dv;
        }
    }
#pragma unroll
    for (int m = 1; m <= 8; m <<= 1) {
#pragma unroll
        for (int r = 0; r < 4; r++) {
            ps[r] += __shfl_xor(ps[r], m, 64);
            pd[r] += __shfl_xor(pd[r], m, 64);
        }
    }
    if (n16 == 0) {
#pragma unroll
        for (int r = 0; r < 4; r++) {
            int node = mbase + r;
            if (node < N) { ssrc[node] = sane(ps[r]); sdst[node] = sane(pd[r]); }
        }
    }
}

// ================= deterministic bucket sort (no global atomics) =================
__global__ __launch_bounds__(1024) void k_cscan(const int* __restrict__ hist,
                                                int gch, int NB,
                                                int* __restrict__ cb,
                                                int* __restrict__ bcount) {
    __shared__ int sh[1024];
    int b = blockIdx.x;
    int t = threadIdx.x;
    int run = 0;
    for (int base = 0; base < gch; base += 1024) {
        int c = base + t;
        int v = (c < gch) ? hist[(long long)c * NB + b] : 0;
        sh[t] = v;
        __syncthreads();
        for (int off = 1; off < 1024; off <<= 1) {
            int xv = (t >= off) ? sh[t - off] : 0;
            __syncthreads();
            sh[t] += xv;
            __syncthreads();
        }
        if (c < gch) cb[(long long)c * NB + b] = run + sh[t] - v;
        run += sh[1023];
        __syncthreads();
    }
    if (t == 0) bcount[b] = run;
}

__global__ void k_bscan(const int* __restrict__ bcount, int NB,
                        int* __restrict__ bbase) {
    __shared__ int sh[NBMAX];
    int t = threadIdx.x;
    int v = (t < NB) ? bcount[t] : 0;
    sh[t] = v;
    __syncthreads();
    for (int off = 1; off < NBMAX; off <<= 1) {
        int xv = (t >= off) ? sh[t - off] : 0;
        __syncthreads();
        sh[t] += xv;
        __syncthreads();
    }
    if (t < NB) bbase[t] = sh[t] - v;
    if (t == NB - 1) bbase[NB] = sh[t];
}

__global__ __launch_bounds__(256) void k_bscatter(const void* __restrict__ ei,
                                                  int E, int N, int NB,
                                                  const int* __restrict__ bbase,
                                                  const int* __restrict__ cb,
                                                  unsigned* __restrict__ binned) {
    __shared__ int rb[NBMAX];
    int tid = threadIdx.x;
    int f = probe_is64((const unsigned*)ei, tid, rb);
    long long cbase = (long long)blockIdx.x * NB;
    for (int i = tid; i < NB; i += 256) rb[i] = bbase[i] + cb[cbase + i];
    __syncthreads();
    long long c0 = (long long)blockIdx.x * CHUNK;
    long long c1 = c0 + CHUNK;
    if (c1 > E) c1 = E;
    for (long long i = c0 + tid; i < c1; i += 256) {
        unsigned d = (unsigned)ldidx(f, ei, (long long)E + i);
        if (d < (unsigned)N) {
            int b = d >> BSHIFT;
            unsigned s = (unsigned)ldidx(f, ei, i);
            if (s >= (unsigned)N) s = 0x00FFFFFFu;  // agg guard drops it (N < 2^24)
            int r = atomicAdd(&rb[b], 1);
            binned[r] = ((d & (unsigned)(BR - 1)) << 24) | s;
        }
    }
}

__global__ __launch_bounds__(256) void k_bbuild(const unsigned* __restrict__ binned,
                                                const int* __restrict__ bbase,
                                                int N, int NB,
                                                int* __restrict__ rowptr,
                                                int* __restrict__ csr_src) {
    __shared__ int ldeg[BR];
    __shared__ int lpos[BR];
    int b = blockIdx.x;
    int t = threadIdx.x;
    int e0 = bbase[b], e1 = bbase[b + 1];
    ldeg[t] = 0;
    __syncthreads();
    for (int i = e0 + t; i < e1; i += 256) {
        atomicAdd(&ldeg[binned[i] >> 24], 1);
    }
    __syncthreads();
    int v = ldeg[t];
    lpos[t] = v;
    __syncthreads();
    for (int off = 1; off < BR; off <<= 1) {
        int xv = (t >= off) ? lpos[t - off] : 0;
        __syncthreads();
        lpos[t] += xv;
        __syncthreads();
    }
    int excl = lpos[t] - v;
    int node = (b << BSHIFT) + t;
    if (node < N) rowptr[node] = e0 + excl;
    if (b == NB - 1 && t == 0) rowptr[N] = e1;
    ldeg[t] = e0 + excl;   // reuse as cursor
    __syncthreads();
    for (int i = e0 + t; i < e1; i += 256) {
        unsigned w = binned[i];
        int p = atomicAdd(&ldeg[w >> 24], 1);
        csr_src[p] = (int)(w & 0x00FFFFFFu);
    }
}

// ================= fallback CSR build (old path, N > 262144) =================
__global__ __launch_bounds__(256) void k_deg(const void* __restrict__ ei,
                                             int E, int N, int* __restrict__ deg) {
    __shared__ int cnt[1];
    int f = probe_is64((const unsigned*)ei, threadIdx.x, cnt);
    int i = blockIdx.x * blockDim.x + threadIdx.x;
    if (i < E) {
        unsigned d = (unsigned)ldidx(f, ei, (long long)E + i);
        if (d < (unsigned)N) atomicAdd(&deg[d], 1);
    }
}

__global__ void k_scan1(const int* __restrict__ deg, int N,
                        int* __restrict__ rowptr, int* __restrict__ bsum) {
    __shared__ int sh[1024];
    int t = threadIdx.x;
    int idx = blockIdx.x * 1024 + t;
    int v = (idx < N) ? deg[idx] : 0;
    sh[t] = v;
    __syncthreads();
    for (int off = 1; off < 1024; off <<= 1) {
        int xv = (t >= off) ? sh[t - off] : 0;
        __syncthreads();
        sh[t] += xv;
        __syncthreads();
    }
    if (idx < N) rowptr[idx] = sh[t] - v;
    if (t == 1023) bsum[blockIdx.x] = sh[1023];
}

__global__ void k_scan2(int* __restrict__ bsum, int B, int* __restrict__ rowptr, int N) {
    __shared__ int sh[1024];
    int t = threadIdx.x;
    int v = (t < B) ? bsum[t] : 0;
    sh[t] = v;
    __syncthreads();
    for (int off = 1; off < 1024; off <<= 1) {
        int xv = (t >= off) ? sh[t - off] : 0;
        __syncthreads();
        sh[t] += xv;
        __syncthreads();
    }
    if (t < B) bsum[t] = sh[t] - v;
    if (t == 1023) rowptr[N] = sh[1023];
}

__global__ void k_scan3(int N, int* __restrict__ rowptr, const int* __restrict__ bsum,
                        int* __restrict__ cursor) {
    int idx = blockIdx.x * 1024 + threadIdx.x;
    if (idx < N) {
        int r = rowptr[idx] + bsum[blockIdx.x];
        rowptr[idx] = r;
        cursor[idx] = r;
    }
}

__global__ __launch_bounds__(256) void k_fill(const void* __restrict__ ei,
                                              int E, int N, int* __restrict__ cursor,
                                              int* __restrict__ csr_src) {
    __shared__ int cnt[1];
    int f = probe_is64((const unsigned*)ei, threadIdx.x, cnt);
    int i = blockIdx.x * blockDim.x + threadIdx.x;
    if (i < E) {
        unsigned d = (unsigned)ldidx(f, ei, (long long)E + i);
        if (d < (unsigned)N) {
            int p = atomicAdd(&cursor[d], 1);
            if ((unsigned)p < (unsigned)E) csr_src[p] = ldidx(f, ei, i);
        }
    }
}

// ---------- FUSED: layer-0 aggregation + skip + ELU -> LDS -> layer-1 MFMA ----------
__global__ __launch_bounds__(512) void k_l0agg_l1(
    const int* __restrict__ rowptr, const int* __restrict__ csr_src,
    const float* __restrict__ ssrc0, const float* __restrict__ sdst0,
    const __hip_bfloat16* __restrict__ h0, const __hip_bfloat16* __restrict__ skip0,
    const void* __restrict__ x,
    const void* W1, const void* sW1, const void* as1, const void* ad1,
    const void* b1, const void* sb1, int N,
    __hip_bfloat16* __restrict__ h1, __hip_bfloat16* __restrict__ skip1,
    float* __restrict__ ssrc1, float* __restrict__ sdst1) {
    __shared__ __hip_bfloat16 xs[4608];     // [64][72]
    __shared__ __hip_bfloat16 wsm[4608];    // wt1[32][72], ws1[32][72]
    __shared__ ull ews[512];                // 8 waves x 64 entries
    __shared__ float psum[64], pdum[64];
    __hip_bfloat16* wt1 = wsm;
    __hip_bfloat16* ws1 = wsm + 2304;
    int tid = threadIdx.x;
    int tile = blockIdx.x * 64;

    int f = probe_isf32((const unsigned*)x, N * 64, tid, (int*)ews);

    {   // stage weights from W1/sW1 directly (transpose): 512 threads x 4 elems
        int i = tid * 4;
        int r = i >> 6, k = i & 63;
        __hip_bfloat16 a0[4], a1[4];
#pragma unroll
        for (int u = 0; u < 4; u++) {
            a0[u] = f2bf(ldany(f, W1,  (k + u) * 32 + r));
            a1[u] = f2bf(ldany(f, sW1, (k + u) * 32 + r));
        }
        *(uint2*)&wt1[r * 72 + k] = *(uint2*)a0;
        *(uint2*)&ws1[r * 72 + k] = *(uint2*)a1;
    }
    if (tid < 64) { psum[tid] = 0.f; pdum[tid] = 0.f; }

    int wv = tid >> 6, lane = tid & 63;
    int half = lane >> 5, l5 = lane & 31;
    int slot = l5 >> 4, c4 = l5 & 15;
    const uint2* h0w = (const uint2*)h0;
    ull* myw = &ews[wv * 64 + half * 32];

    // ---- aggregation phase: 4 passes, 16 nodes each ----
    for (int pass = 0; pass < 4; pass++) {
        int row = pass * 16 + wv * 2 + half;
        int n = tile + row;
        bool act = n < N;
        int nn = act ? n : 0;

        float sd = sdst0[nn];
        float wself = ewgt(ssrc0[nn] + sd);

        uint2 selfv = h0w[(size_t)nn * 16 + c4];
        float w0 = (slot == 0) ? wself : 0.f;
        float acc0 = w0 * bflo(selfv.x);
        float acc1 = w0 * bfhi(selfv.x);
        float acc2 = w0 * bflo(selfv.y);
        float acc3 = w0 * bfhi(selfv.y);
        float denp = 0.f;

        int beg = act ? rowptr[nn] : 0;
        int end = act ? rowptr[nn + 1] : 0;
        for (int j0 = beg; j0 < end; j0 += 32) {
            int cnt = end - j0; if (cnt > 32) cnt = 32;
            int s = (l5 < cnt) ? csr_src[j0 + l5] : 0;
            bool v = (l5 < cnt) && ((unsigned)s < (unsigned)N);
            int sg = v ? s : 0;
            float wj = v ? ewgt(ssrc0[sg] + sd) : 0.f;
            denp += wj;
            myw[l5] = ((ull)__float_as_uint(wj) << 32) | (unsigned)sg;
            int k2 = 0;
            int full = cnt & ~7;
            for (; k2 < full; k2 += 8) {
                ull pa = myw[k2 + slot];
                ull pb = myw[k2 + 2 + slot];
                ull pc = myw[k2 + 4 + slot];
                ull pd_ = myw[k2 + 6 + slot];
                float wa = __uint_as_float((unsigned)(pa >> 32));
                float wb = __uint_as_float((unsigned)(pb >> 32));
                float wc = __uint_as_float((unsigned)(pc >> 32));
                float wd = __uint_as_float((unsigned)(pd_ >> 32));
                int sa = (int)(unsigned)(pa & 0xffffffffu);
                int sb = (int)(unsigned)(pb & 0xffffffffu);
                int sc = (int)(unsigned)(pc & 0xffffffffu);
                int sdi = (int)(unsigned)(pd_ & 0xffffffffu);
                uint2 va = h0w[(size_t)sa * 16 + c4];
                uint2 vb = h0w[(size_t)sb * 16 + c4];
                uint2 vc = h0w[(size_t)sc * 16 + c4];
                uint2 vd = h0w[(size_t)sdi * 16 + c4];
                acc0 += wa * bflo(va.x) + wb * bflo(vb.x) + wc * bflo(vc.x) + wd * bflo(vd.x);
                acc1 += wa * bfhi(va.x) + wb * bfhi(vb.x) + wc * bfhi(vc.x) + wd * bfhi(vd.x);
                acc2 += wa * bflo(va.y) + wb * bflo(vb.y) + wc * bflo(vc.y) + wd * bflo(vd.y);
                acc3 += wa * bfhi(va.y) + wb * bfhi(vb.y) + wc * bfhi(vc.y) + wd * bfhi(vd.y);
            }
            for (; k2 < cnt; k2 += 8) {
                int ia = k2 + slot,     ib = k2 + 2 + slot;
                int ic = k2 + 4 + slot, id = k2 + 6 + slot;
                ull pa = myw[ia < cnt ? ia : 0];
                ull pb = myw[ib < cnt ? ib : 0];
                ull pc = myw[ic < cnt ? ic : 0];
                ull pd_ = myw[id < cnt ? id : 0];
                float wa = (ia < cnt) ? __uint_as_float((unsigned)(pa >> 32)) : 0.f;
                float wb = (ib < cnt) ? __uint_as_float((unsigned)(pb >> 32)) : 0.f;
                float wc = (ic < cnt) ? __uint_as_float((unsigned)(pc >> 32)) : 0.f;
                float wd = (id < cnt) ? __uint_as_float((unsigned)(pd_ >> 32)) : 0.f;
                int sa = (int)(unsigned)(pa & 0xffffffffu);
                int sb = (int)(unsigned)(pb & 0xffffffffu);
                int sc = (int)(unsigned)(pc & 0xffffffffu);
                int sdi = (int)(unsigned)(pd_ & 0xffffffffu);
                uint2 va = h0w[(size_t)sa * 16 + c4];
                uint2 vb = h0w[(size_t)sb * 16 + c4];
                uint2 vc = h0w[(size_t)sc * 16 + c4];
                uint2 vd = h0w[(size_t)sdi * 16 + c4];
                acc0 += wa * bflo(va.x) + wb * bflo(vb.x) + wc * bflo(vc.x) + wd * bflo(vd.x);
                acc1 += wa * bfhi(va.x) + wb * bfhi(vb.x) + wc * bfhi(vc.x) + wd * bfhi(vd.x);
                acc2 += wa * bflo(va.y) + wb * bflo(vb.y) + wc * bflo(vc.y) + wd * bflo(vd.y);
                acc3 += wa * bfhi(va.y) + wb * bfhi(vb.y) + wc * bfhi(vc.y) + wd * bfhi(vd.y);
            }
        }
        acc0 += __shfl_xor(acc0, 16, 64);
        acc1 += __shfl_xor(acc1, 16, 64);
        acc2 += __shfl_xor(acc2, 16, 64);
        acc3 += __shfl_xor(acc3, 16, 64);
        float den = denp;
#pragma unroll
        for (int m = 1; m <= 16; m <<= 1) den += __shfl_xor(den, m, 64);
        den += wself;

        if (slot == 0) {
            uint2 o; o.x = 0u; o.y = 0u;
            if (act) {
                uint2 skv = ((const uint2*)skip0)[(size_t)nn * 16 + c4];
                float v0 = sane(acc0 / den + bflo(skv.x));
                float v1 = sane(acc1 / den + bfhi(skv.x));
                float v2 = sane(acc2 / den + bflo(skv.y));
                float v3 = sane(acc3 / den + bfhi(skv.y));
                v0 = v0 > 0.f ? v0 : (__expf(v0) - 1.f);   // ELU
                v1 = v1 > 0.f ? v1 : (__expf(v1) - 1.f);
                v2 = v2 > 0.f ? v2 : (__expf(v2) - 1.f);
                v3 = v3 > 0.f ? v3 : (__expf(v3) - 1.f);
                o.x = packbf(v0, v1);
                o.y = packbf(v2, v3);
            }
            *(uint2*)&xs[row * 72 + c4 * 4] = o;
        }
    }
    __syncthreads();

    // ---- layer-1 MFMA phase: wave -> rowtile rt, coltile ct ----
    int rt = wv >> 1, ct = wv & 1;
    int n16 = lane & 15, quad = lane >> 4;
    v4f acc_h = {0.f, 0.f, 0.f, 0.f};
    v4f acc_s = {0.f, 0.f, 0.f, 0.f};
    int arow = rt * 16 + n16;
#pragma unroll
    for (int s = 0; s < 2; s++) {
        v8s a = ld8(&xs[arow * 72 + s * 32 + (quad << 3)]);
        v8s bh = ld8(&wt1[(ct * 16 + n16) * 72 + s * 32 + (quad << 3)]);
        acc_h = __builtin_amdgcn_mfma_f32_16x16x32_bf16(a, bh, acc_h, 0, 0, 0);
        v8s bs = ld8(&ws1[(ct * 16 + n16) * 72 + s * 32 + (quad << 3)]);
        acc_s = __builtin_amdgcn_mfma_f32_16x16x32_bf16(a, bs, acc_s, 0, 0, 0);
    }

    int mrow = rt * 16 + (quad << 2);
    int mbase = tile + mrow;
    int ch = ct * 16 + n16;
    float av = ldany(f, as1, ch);
    float dv = ldany(f, ad1, ch);
    float bv = ldany(f, b1, ch) + ldany(f, sb1, ch);
    float ps[4] = {0, 0, 0, 0}, pd[4] = {0, 0, 0, 0};
#pragma unroll
    for (int r = 0; r < 4; r++) {
        float hv = sane(acc_h[r]);
        float sv = sane(acc_s[r] + bv);
        int node = mbase + r;
        if (node < N) {
            h1[(size_t)node * 32 + ch] = f2bf(hv);
            skip1[(size_t)node * 32 + ch] = f2bf(sv);
        }
        ps[r] += hv * av;
        pd[r] += hv * dv;
    }
#pragma unroll
    for (int m = 1; m <= 8; m <<= 1) {
#pragma unroll
        for (int r = 0; r < 4; r++) {
            ps[r] += __shfl_xor(ps[r], m, 64);
            pd[r] += __shfl_xor(pd[r], m, 64);
        }
    }
    if (n16 == 0) {
#pragma unroll
        for (int r = 0; r < 4; r++) {
            atomicAdd(&psum[mrow + r], ps[r]);
            atomicAdd(&pdum[mrow + r], pd[r]);
        }
    }
    __syncthreads();
    if (tid < 64) {
        int node = tile + tid;
        if (node < N) {
            ssrc1[node] = sane(psum[tid]);
            sdst1[node] = sane(pdum[tid]);
        }
    }
}

// ---------- layer 1 aggregation: 2 nodes/wave, full-group fast path, log_softmax ----------
__global__ __launch_bounds__(256) void k_l1_agg(
    const int* __restrict__ rowptr, const int* __restrict__ csr_src,
    const float* __restrict__ ssrc, const float* __restrict__ sdst,
    const __hip_bfloat16* __restrict__ h1, const __hip_bfloat16* __restrict__ skip1,
    int N, float* __restrict__ out) {
    __shared__ ull ews[256];
    int wv = threadIdx.x >> 6, lane = threadIdx.x & 63;
    int half = lane >> 5, l5 = lane & 31;
    int slot = l5 >> 3, c4 = l5 & 7;      // slot 0..3; channels 4*c4..4*c4+3
    int n = blockIdx.x * 8 + wv * 2 + half;
    bool act = n < N;
    int nn = act ? n : 0;
    const uint2* h1w = (const uint2*)h1;
    ull* myw = &ews[wv * 64 + half * 32];

    float sd = sdst[nn];
    float wself = ewgt(ssrc[nn] + sd);

    uint2 selfv = h1w[(size_t)nn * 8 + c4];
    float w0 = (slot == 0) ? wself : 0.f;
    float acc0 = w0 * bflo(selfv.x);
    float acc1 = w0 * bfhi(selfv.x);
    float acc2 = w0 * bflo(selfv.y);
    float acc3 = w0 * bfhi(selfv.y);
    float denp = 0.f;

    int beg = act ? rowptr[nn] : 0;
    int end = act ? rowptr[nn + 1] : 0;
    for (int j0 = beg; j0 < end; j0 += 32) {
        int cnt = end - j0; if (cnt > 32) cnt = 32;
        int s = (l5 < cnt) ? csr_src[j0 + l5] : 0;
        bool v = (l5 < cnt) && ((unsigned)s < (unsigned)N);
        int sg = v ? s : 0;
        float wj = v ? ewgt(ssrc[sg] + sd) : 0.f;
        denp += wj;
        myw[l5] = ((ull)__float_as_uint(wj) << 32) | (unsigned)sg;
        int k4 = 0;
        int full = cnt & ~15;
        for (; k4 < full; k4 += 16) {
            ull pa = myw[k4 + slot];
            ull pb = myw[k4 + 4 + slot];
            ull pc = myw[k4 + 8 + slot];
            ull pd_ = myw[k4 + 12 + slot];
            float wa = __uint_as_float((unsigned)(pa >> 32));
            float wb = __uint_as_float((unsigned)(pb >> 32));
            float wc = __uint_as_float((unsigned)(pc >> 32));
            float wd = __uint_as_float((unsigned)(pd_ >> 32));
            int sa = (int)(unsigned)(pa & 0xffffffffu);
            int sb = (int)(unsigned)(pb & 0xffffffffu);
            int sc = (int)(unsigned)(pc & 0xffffffffu);
            int sdi = (int)(unsigned)(pd_ & 0xffffffffu);
            uint2 va = h1w[(size_t)sa * 8 + c4];
            uint2 vb = h1w[(size_t)sb * 8 + c4];
            uint2 vc = h1w[(size_t)sc * 8 + c4];
            uint2 vd = h1w[(size_t)sdi * 8 + c4];
            acc0 += wa * bflo(va.x) + wb * bflo(vb.x) + wc * bflo(vc.x) + wd * bflo(vd.x);
            acc1 += wa * bfhi(va.x) + wb * bfhi(vb.x) + wc * bfhi(vc.x) + wd * bfhi(vd.x);
            acc2 += wa * bflo(va.y) + wb * bflo(vb.y) + wc * bflo(vc.y) + wd * bflo(vd.y);
            acc3 += wa * bfhi(va.y) + wb * bfhi(vb.y) + wc * bfhi(vc.y) + wd * bfhi(vd.y);
        }
        for (; k4 < cnt; k4 += 16) {
            int ia = k4 + slot,      ib = k4 + 4 + slot;
            int ic = k4 + 8 + slot,  id = k4 + 12 + slot;
            ull pa = myw[ia < cnt ? ia : 0];
            ull pb = myw[ib < cnt ? ib : 0];
            ull pc = myw[ic < cnt ? ic : 0];
            ull pd_ = myw[id < cnt ? id : 0];
            float wa = (ia < cnt) ? __uint_as_float((unsigned)(pa >> 32)) : 0.f;
            float wb = (ib < cnt) ? __uint_as_float((unsigned)(pb >> 32)) : 0.f;
            float wc = (ic < cnt) ? __uint_as_float((unsigned)(pc >> 32)) : 0.f;
            float wd = (id < cnt) ? __uint_as_float((unsigned)(pd_ >> 32)) : 0.f;
            int sa = (int)(unsigned)(pa & 0xffffffffu);
            int sb = (int)(unsigned)(pb & 0xffffffffu);
            int sc = (int)(unsigned)(pc & 0xffffffffu);
            int sdi = (int)(unsigned)(pd_ & 0xffffffffu);
            uint2 va = h1w[(size_t)sa * 8 + c4];
            uint2 vb = h1w[(size_t)sb * 8 + c4];
            uint2 vc = h1w[(size_t)sc * 8 + c4];
            uint2 vd = h1w[(size_t)sdi * 8 + c4];
            acc0 += wa * bflo(va.x) + wb * bflo(vb.x) + wc * bflo(vc.x) + wd * bflo(vd.x);
            acc1 += wa * bfhi(va.x) + wb * bfhi(vb.x) + wc * bfhi(vc.x) + wd * bfhi(vd.x);
            acc2 += wa * bflo(va.y) + wb * bflo(vb.y) + wc * bflo(vc.y) + wd * bflo(vd.y);
            acc3 += wa * bfhi(va.y) + wb * bfhi(vb.y) + wc * bfhi(vc.y) + wd * bfhi(vd.y);
        }
    }
    acc0 += __shfl_xor(acc0, 8, 64); acc0 += __shfl_xor(acc0, 16, 64);
    acc1 += __shfl_xor(acc1, 8, 64); acc1 += __shfl_xor(acc1, 16, 64);
    acc2 += __shfl_xor(acc2, 8, 64); acc2 += __shfl_xor(acc2, 16, 64);
    acc3 += __shfl_xor(acc3, 8, 64); acc3 += __shfl_xor(acc3, 16, 64);
    float den = denp;
#pragma unroll
    for (int m = 1; m <= 16; m <<= 1) den += __shfl_xor(den, m, 64);
    den += wself;

    uint2 skv = ((const uint2*)skip1)[(size_t)nn * 8 + c4];
    float o0 = sane(acc0 / den + bflo(skv.x));
    float o1 = sane(acc1 / den + bfhi(skv.x));
    float o2 = sane(acc2 / den + bflo(skv.y));
    float o3 = sane(acc3 / den + bfhi(skv.y));
    float m = fmaxf(fmaxf(o0, o1), fmaxf(o2, o3));
#pragma unroll
    for (int k = 1; k <= 4; k <<= 1) m = fmaxf(m, __shfl_xor(m, k, 64));
    float ex = __expf(o0 - m) + __expf(o1 - m) + __expf(o2 - m) + __expf(o3 - m);
#pragma unroll
    for (int k = 1; k <= 4; k <<= 1) ex += __shfl_xor(ex, k, 64);
    float l = __logf(ex);
    float r0 = o0 - m - l, r1 = o1 - m - l, r2 = o2 - m - l, r3 = o3 - m - l;
    if (!isfinite(r0)) r0 = 0.f;
    if (!isfinite(r1)) r1 = 0.f;
    if (!isfinite(r2)) r2 = 0.f;
    if (!isfinite(r3)) r3 = 0.f;
    if (slot == 0 && act) {
        float4 o4; o4.x = r0; o4.y = r1; o4.z = r2; o4.w = r3;
        *(float4*)&out[(size_t)nn * 32 + 4 * c4] = o4;
    }
}

__global__ void k_zero(int* __restrict__ p, int n) {
    int i = blockIdx.x * blockDim.x + threadIdx.x;
    if (i < n) p[i] = 0;
}

__global__ void k_sentinel(float* __restrict__ out, int n, float val) {
    int i = blockIdx.x * blockDim.x + threadIdx.x;
    if (i < n) out[i] = val;
}

extern "C" void kernel_launch(void* const* d_in, const int* in_sizes, int n_in,
                              void* d_out, int out_size, void* d_ws, size_t ws_size,
                              hipStream_t stream) {
    const void* x  = d_in[0];
    const void* ei = d_in[1];
    float* out = (float*)d_out;

    int N = in_sizes[0] / 128;
    int E = in_sizes[1] / 2;

    int NB  = (N + BR - 1) >> BSHIFT;
    int gch = (E + CHUNK - 1) / CHUNK;
    if (gch < 1) gch = 1;
    int Lb = (N + 63) / 64;
    bool fast = (N <= (NBMAX << BSHIFT)) && ((size_t)E * 4 <= (size_t)N * 128);

    char* ws = (char*)d_ws;
    size_t off = 0;
    auto alloc = [&](size_t bytes) -> char* {
        char* p = ws + off;
        off += (bytes + 255) & ~(size_t)255;
        return p;
    };
    int*   rowptr  = (int*)alloc((size_t)(N + 1) * 4);
    int*   cursor  = (int*)alloc((size_t)N * 4);          // -> ssrc0 overlay after CSR
    float* sdst0   = (float*)alloc((size_t)N * 4);
    float* ssrc1   = (float*)alloc((size_t)N * 4);
    float* sdst1   = (float*)alloc((size_t)N * 4);
    int*   bsum    = (int*)alloc(1024 * 4);
    int*   bcount  = (int*)alloc(NBMAX * 4);
    int*   bbase   = (int*)alloc((NBMAX + 1) * 4);
    int*   csr_src = (int*)alloc((size_t)E * 4);
    unsigned* binned = (unsigned*)alloc(fast ? (size_t)E * 4 : 0);
    int*   hist    = (int*)alloc(fast ? (size_t)gch * NB * 4 : 0);
    int*   cb      = (int*)alloc(fast ? (size_t)gch * NB * 4 : 0);
    __hip_bfloat16* h0    = (__hip_bfloat16*)alloc((size_t)N * 64 * 2);
    __hip_bfloat16* skip0 = (__hip_bfloat16*)alloc((size_t)N * 64 * 2);
    __hip_bfloat16* h1    = (__hip_bfloat16*)alloc((size_t)N * 32 * 2);
    __hip_bfloat16* skip1 = (__hip_bfloat16*)alloc((size_t)N * 32 * 2);
    size_t required = off;

    if (ws_size < required) {
        float mb = (float)(double)(ws_size >> 20);
        k_sentinel<<<(out_size + 255) / 256, 256, 0, stream>>>(out, out_size, mb);
        return;
    }

    float* ssrc0 = (float*)cursor;

    if (fast) {
        // K1: chist (blocks 0..gch) + layer-0 transform (blocks gch..gch+Lb) — independent, overlapped
        k1_chist_l0<<<gch + Lb, 256, 0, stream>>>(ei, x, d_in[2], d_in[6], d_in[3], d_in[4],
                                                  d_in[5], d_in[7], N, E, NB, gch, hist,
                                                  h0, skip0, ssrc0, sdst0);
        k_cscan<<<NB, 1024, 0, stream>>>(hist, gch, NB, cb, bcount);
        k_bscan<<<1, NBMAX, 0, stream>>>(bcount, NB, bbase);
        k_bscatter<<<gch, 256, 0, stream>>>(ei, E, N, NB, bbase, cb, binned);
        k_bbuild<<<NB, 256, 0, stream>>>(binned, bbase, N, NB, rowptr, csr_src);
    } else {
        int B = (N + 1023) / 1024;
        k_zero<<<(N + 255) / 256, 256, 0, stream>>>(cursor, N);
        k_deg<<<(E + 255) / 256, 256, 0, stream>>>(ei, E, N, cursor);
        k_scan1<<<B, 1024, 0, stream>>>(cursor, N, rowptr, bsum);
        k_scan2<<<1, 1024, 0, stream>>>(bsum, B, rowptr, N);
        k_scan3<<<B, 1024, 0, stream>>>(N, rowptr, bsum, cursor);
        k_fill<<<(E + 255) / 256, 256, 0, stream>>>(ei, E, N, cursor, csr_src);
        k1_chist_l0<<<Lb, 256, 0, stream>>>(ei, x, d_in[2], d_in[6], d_in[3], d_in[4],
                                            d_in[5], d_in[7], N, E, NB, 0, hist,
                                            h0, skip0, ssrc0, sdst0);
    }

    k_l0agg_l1<<<Lb, 512, 0, stream>>>(rowptr, csr_src, ssrc0, sdst0,
                                       h0, skip0, x,
                                       d_in[8], d_in[12], d_in[9], d_in[10],
                                       d_in[11], d_in[13], N,
                                       h1, skip1, ssrc1, sdst1);
    k_l1_agg<<<(N + 7) / 8, 256, 0, stream>>>(rowptr, csr_src, ssrc1, sdst1,
                                              h1, skip1, N, out);
}

// Round 10
// 277.739 us; speedup vs baseline: 1.1581x; 1.1581x over previous
//
#include <hip/hip_runtime.h>
#include <hip/hip_bf16.h>
#include <math.h>

#define NEG_SLOPE 0.2f
#define ECLAMP 30.0f
#define HCLAMP 1.0e4f

#define BSHIFT 8
#define BR 256
#define NBMAX 1024
#define CHUNK 2048

typedef short v8s __attribute__((ext_vector_type(8)));
typedef float v4f __attribute__((ext_vector_type(4)));
typedef unsigned long long ull;

__device__ __forceinline__ float bf2f(__hip_bfloat16 v) { return __bfloat162float(v); }
__device__ __forceinline__ __hip_bfloat16 f2bf(float v) { return __float2bfloat16(v); }
__device__ __forceinline__ float sane(float v)   { return fminf(fmaxf(v, -HCLAMP), HCLAMP); }
__device__ __forceinline__ float eclampf(float v){ return fminf(fmaxf(v, -ECLAMP), ECLAMP); }

__device__ __forceinline__ float ldany(int isf32, const void* p, int i) {
    return isf32 ? ((const float*)p)[i] : bf2f(((const __hip_bfloat16*)p)[i]);
}
__device__ __forceinline__ int ldidx(int is64, const void* p, long long i) {
    return is64 ? (int)((const long long*)p)[i] : ((const int*)p)[i];
}
__device__ __forceinline__ v8s ld8(const __hip_bfloat16* p) { return *(const v8s*)p; }

// leaky_relu + clamp + exp
__device__ __forceinline__ float ewgt(float e) {
    e = e > 0.f ? e : NEG_SLOPE * e;
    return __expf(eclampf(e));
}

__device__ __forceinline__ float bflo(unsigned v) { return __uint_as_float(v << 16); }
__device__ __forceinline__ float bfhi(unsigned v) { return __uint_as_float(v & 0xffff0000u); }
__device__ __forceinline__ unsigned packbf(float a, float b) {
    __hip_bfloat16 x = f2bf(a), y = f2bf(b);
    return (unsigned)(*(unsigned short*)&x) | ((unsigned)(*(unsigned short*)&y) << 16);
}

// ---------- dtype probe ----------
__global__ void k_probe(const unsigned* __restrict__ xw, int nw_safe,
                        const unsigned* __restrict__ ew, int* __restrict__ flags) {
    __shared__ int cnt[2];
    int t = threadIdx.x;
    if (t < 2) cnt[t] = 0;
    __syncthreads();
    unsigned w = xw[(unsigned)(t * 9973) % (unsigned)nw_safe];
    unsigned lo = w & 0xffffu;
    unsigned exp = (lo >> 7) & 0xffu;
    if (lo != 0u && (exp < 90u || exp > 160u)) atomicAdd(&cnt[0], 1);
    if (ew[2 * t + 1] == 0u) atomicAdd(&cnt[1], 1);
    __syncthreads();
    if (t == 0) { flags[0] = (2 * cnt[0] > 256) ? 1 : 0; flags[1] = (cnt[1] >= 200) ? 1 : 0; }
}

// ---------- params: Pf fp32 vectors + transposed bf16 weights ----------
__global__ void k_params(const int* __restrict__ flags,
                         const void* W0, const void* sW0, const void* as0, const void* ad0,
                         const void* b0, const void* sb0, const void* W1, const void* sW1,
                         const void* as1, const void* ad1, const void* b1, const void* sb1,
                         float* __restrict__ Pf, __hip_bfloat16* __restrict__ Wg) {
    int f = flags[0];
    int t = blockIdx.x * blockDim.x + threadIdx.x;
    int T = gridDim.x * blockDim.x;
    for (int i = t; i < 8192; i += T) {
        int n = i >> 7, k = i & 127;
        Wg[i]        = f2bf(ldany(f, W0,  k * 64 + n));
        Wg[8192 + i] = f2bf(ldany(f, sW0, k * 64 + n));
    }
    for (int i = t; i < 2048; i += T) {
        int n = i >> 6, k = i & 63;
        Wg[16384 + i] = f2bf(ldany(f, W1,  k * 32 + n));
        Wg[18432 + i] = f2bf(ldany(f, sW1, k * 32 + n));
    }
    if (t < 64) {
        Pf[t]       = ldany(f, as0, t);
        Pf[64 + t]  = ldany(f, ad0, t);
        Pf[128 + t] = ldany(f, b0, t) + ldany(f, sb0, t);
    }
    if (t < 32) {
        Pf[192 + t] = ldany(f, as1, t);
        Pf[224 + t] = ldany(f, ad1, t);
        Pf[256 + t] = ldany(f, b1, t) + ldany(f, sb1, t);
    }
}

__global__ void k_zero(int* __restrict__ p, int n) {
    int i = blockIdx.x * blockDim.x + threadIdx.x;
    if (i < n) p[i] = 0;
}

// ================= MERGED: chunk histogram (blocks < gch) ∪ layer-0 transform =================
// chist blocks use 4KB of the shared buffer; l0 blocks use all 52224B (same as R7's k_l0).
__global__ __launch_bounds__(256) void k1_chist_l0(
    const void* __restrict__ ei, const void* __restrict__ x,
    const int* __restrict__ flags,
    const float* __restrict__ Pf, const __hip_bfloat16* __restrict__ Wg,
    int N, int E, int NB, int gch,
    int* __restrict__ hist,
    __hip_bfloat16* __restrict__ h0, __hip_bfloat16* __restrict__ skip0,
    float* __restrict__ ssrc, float* __restrict__ sdst) {
    __shared__ __align__(16) char smraw[52224];
    int tid = threadIdx.x;

    if ((int)blockIdx.x < gch) {
        // ---------- chist part ----------
        int f = flags[1];
        int* h = (int*)smraw;
        for (int i = tid; i < NB; i += 256) h[i] = 0;
        __syncthreads();
        long long c0 = (long long)blockIdx.x * CHUNK;
        long long c1 = c0 + CHUNK;
        if (c1 > E) c1 = E;
        for (long long i = c0 + tid; i < c1; i += 256) {
            unsigned d = (unsigned)ldidx(f, ei, (long long)E + i);
            if (d < (unsigned)N) atomicAdd(&h[d >> BSHIFT], 1);
        }
        __syncthreads();
        long long base = (long long)blockIdx.x * NB;
        for (int i = tid; i < NB; i += 256) hist[base + i] = h[i];
        return;
    }

    // ---------- layer-0 transform part (identical to R7's k_l0) ----------
    __hip_bfloat16* xs  = (__hip_bfloat16*)smraw;
    __hip_bfloat16* wt0 = xs + 8704;
    __hip_bfloat16* wts = xs + 17408;
    int f = flags[0];
    int tile = ((int)blockIdx.x - gch) * 64;

    for (int i = tid * 4; i < 8192; i += 1024) {
        int r = i >> 7, k = i & 127;
        uint2 w0v = *(const uint2*)&Wg[i];
        uint2 w1v = *(const uint2*)&Wg[8192 + i];
        *(uint2*)&wt0[r * 136 + k] = w0v;
        *(uint2*)&wts[r * 136 + k] = w1v;
    }
    for (int i = tid * 4; i < 8192; i += 1024) {
        int r = i >> 7, k = i & 127;
        int g = tile + r; if (g >= N) g = N - 1;
        uint2* dx = (uint2*)&xs[r * 136 + k];
        if (f) {
            float4 v = *(const float4*)((const float*)x + (size_t)g * 128 + k);
            uint2 o; o.x = packbf(v.x, v.y); o.y = packbf(v.z, v.w);
            *dx = o;
        } else {
            *dx = *(const uint2*)((const __hip_bfloat16*)x + (size_t)g * 128 + k);
        }
    }
    __syncthreads();

    int lane = tid & 63, w = tid >> 6;
    int n16 = lane & 15, quad = lane >> 4;
    v4f zf = {0.f, 0.f, 0.f, 0.f};
    v4f acc_h[4], acc_s[4];
#pragma unroll
    for (int t = 0; t < 4; t++) { acc_h[t] = zf; acc_s[t] = zf; }

    int arow = (w << 4) + n16;
#pragma unroll
    for (int s = 0; s < 4; s++) {
        v8s a = ld8(&xs[arow * 136 + s * 32 + (quad << 3)]);
#pragma unroll
        for (int t = 0; t < 4; t++) {
            v8s bh = ld8(&wt0[(t * 16 + n16) * 136 + s * 32 + (quad << 3)]);
            acc_h[t] = __builtin_amdgcn_mfma_f32_16x16x32_bf16(a, bh, acc_h[t], 0, 0, 0);
            v8s bs = ld8(&wts[(t * 16 + n16) * 136 + s * 32 + (quad << 3)]);
            acc_s[t] = __builtin_amdgcn_mfma_f32_16x16x32_bf16(a, bs, acc_s[t], 0, 0, 0);
        }
    }

    int mbase = tile + (w << 4) + (quad << 2);
    float ps[4] = {0, 0, 0, 0}, pd[4] = {0, 0, 0, 0};
#pragma unroll
    for (int t = 0; t < 4; t++) {
        int ch = t * 16 + n16;
        float av = Pf[ch];
        float dv = Pf[64 + ch];
        float bv = Pf[128 + ch];
#pragma unroll
        for (int r = 0; r < 4; r++) {
            float hv = sane(acc_h[t][r]);
            float sv = sane(acc_s[t][r] + bv);
            int node = mbase + r;
            if (node < N) {
                h0[(size_t)node * 64 + ch] = f2bf(hv);
                skip0[(size_t)node * 64 + ch] = f2bf(sv);
            }
            ps[r] += hv * av;
            pd[r] += hv * dv;
        }
    }
#pragma unroll
    for (int m = 1; m <= 8; m <<= 1) {
#pragma unroll
        for (int r = 0; r < 4; r++) {
            ps[r] += __shfl_xor(ps[r], m, 64);
            pd[r] += __shfl_xor(pd[r], m, 64);
        }
    }
    if (n16 == 0) {
#pragma unroll
        for (int r = 0; r < 4; r++) {
            int node = mbase + r;
            if (node < N) { ssrc[node] = sane(ps[r]); sdst[node] = sane(pd[r]); }
        }
    }
}

// ================= deterministic bucket sort (no global atomics) =================
__global__ __launch_bounds__(1024) void k_cscan(const int* __restrict__ hist,
                                                int gch, int NB,
                                                int* __restrict__ cb,
                                                int* __restrict__ bcount) {
    __shared__ int sh[1024];
    int b = blockIdx.x;
    int t = threadIdx.x;
    int run = 0;
    for (int base = 0; base < gch; base += 1024) {
        int c = base + t;
        int v = (c < gch) ? hist[(long long)c * NB + b] : 0;
        sh[t] = v;
        __syncthreads();
        for (int off = 1; off < 1024; off <<= 1) {
            int xv = (t >= off) ? sh[t - off] : 0;
            __syncthreads();
            sh[t] += xv;
            __syncthreads();
        }
        if (c < gch) cb[(long long)c * NB + b] = run + sh[t] - v;
        run += sh[1023];
        __syncthreads();
    }
    if (t == 0) bcount[b] = run;
}

__global__ void k_bscan(const int* __restrict__ bcount, int NB,
                        int* __restrict__ bbase) {
    __shared__ int sh[NBMAX];
    int t = threadIdx.x;
    int v = (t < NB) ? bcount[t] : 0;
    sh[t] = v;
    __syncthreads();
    for (int off = 1; off < NBMAX; off <<= 1) {
        int xv = (t >= off) ? sh[t - off] : 0;
        __syncthreads();
        sh[t] += xv;
        __syncthreads();
    }
    if (t < NB) bbase[t] = sh[t] - v;
    if (t == NB - 1) bbase[NB] = sh[t];
}

__global__ __launch_bounds__(256) void k_bscatter(const void* __restrict__ ei,
                                                  const int* __restrict__ flags,
                                                  int E, int N, int NB,
                                                  const int* __restrict__ bbase,
                                                  const int* __restrict__ cb,
                                                  unsigned* __restrict__ binned) {
    __shared__ int rb[NBMAX];
    int f = flags[1];
    long long cbase = (long long)blockIdx.x * NB;
    for (int i = threadIdx.x; i < NB; i += 256) rb[i] = bbase[i] + cb[cbase + i];
    __syncthreads();
    long long c0 = (long long)blockIdx.x * CHUNK;
    long long c1 = c0 + CHUNK;
    if (c1 > E) c1 = E;
    for (long long i = c0 + threadIdx.x; i < c1; i += 256) {
        unsigned d = (unsigned)ldidx(f, ei, (long long)E + i);
        if (d < (unsigned)N) {
            int b = d >> BSHIFT;
            unsigned s = (unsigned)ldidx(f, ei, i);
            if (s >= (unsigned)N) s = 0x00FFFFFFu;  // agg guard drops it (N < 2^24)
            int r = atomicAdd(&rb[b], 1);
            binned[r] = ((d & (unsigned)(BR - 1)) << 24) | s;
        }
    }
}

__global__ __launch_bounds__(256) void k_bbuild(const unsigned* __restrict__ binned,
                                                const int* __restrict__ bbase,
                                                int N, int NB,
                                                int* __restrict__ rowptr,
                                                int* __restrict__ csr_src) {
    __shared__ int ldeg[BR];
    __shared__ int lpos[BR];
    int b = blockIdx.x;
    int t = threadIdx.x;
    int e0 = bbase[b], e1 = bbase[b + 1];
    ldeg[t] = 0;
    __syncthreads();
    for (int i = e0 + t; i < e1; i += 256) {
        atomicAdd(&ldeg[binned[i] >> 24], 1);
    }
    __syncthreads();
    int v = ldeg[t];
    lpos[t] = v;
    __syncthreads();
    for (int off = 1; off < BR; off <<= 1) {
        int xv = (t >= off) ? lpos[t - off] : 0;
        __syncthreads();
        lpos[t] += xv;
        __syncthreads();
    }
    int excl = lpos[t] - v;
    int node = (b << BSHIFT) + t;
    if (node < N) rowptr[node] = e0 + excl;
    if (b == NB - 1 && t == 0) rowptr[N] = e1;
    ldeg[t] = e0 + excl;   // reuse as cursor
    __syncthreads();
    for (int i = e0 + t; i < e1; i += 256) {
        unsigned w = binned[i];
        int p = atomicAdd(&ldeg[w >> 24], 1);
        csr_src[p] = (int)(w & 0x00FFFFFFu);
    }
}

// ================= fallback CSR build (old path, N > 262144) =================
__global__ void k_deg(const void* __restrict__ ei, const int* __restrict__ flags,
                      int E, int N, int* __restrict__ deg) {
    int i = blockIdx.x * blockDim.x + threadIdx.x;
    if (i < E) {
        unsigned d = (unsigned)ldidx(flags[1], ei, (long long)E + i);
        if (d < (unsigned)N) atomicAdd(&deg[d], 1);
    }
}

__global__ void k_scan1(const int* __restrict__ deg, int N,
                        int* __restrict__ rowptr, int* __restrict__ bsum) {
    __shared__ int sh[1024];
    int t = threadIdx.x;
    int idx = blockIdx.x * 1024 + t;
    int v = (idx < N) ? deg[idx] : 0;
    sh[t] = v;
    __syncthreads();
    for (int off = 1; off < 1024; off <<= 1) {
        int xv = (t >= off) ? sh[t - off] : 0;
        __syncthreads();
        sh[t] += xv;
        __syncthreads();
    }
    if (idx < N) rowptr[idx] = sh[t] - v;
    if (t == 1023) bsum[blockIdx.x] = sh[1023];
}

__global__ void k_scan2(int* __restrict__ bsum, int B, int* __restrict__ rowptr, int N) {
    __shared__ int sh[1024];
    int t = threadIdx.x;
    int v = (t < B) ? bsum[t] : 0;
    sh[t] = v;
    __syncthreads();
    for (int off = 1; off < 1024; off <<= 1) {
        int xv = (t >= off) ? sh[t - off] : 0;
        __syncthreads();
        sh[t] += xv;
        __syncthreads();
    }
    if (t < B) bsum[t] = sh[t] - v;
    if (t == 1023) rowptr[N] = sh[1023];
}

__global__ void k_scan3(int N, int* __restrict__ rowptr, const int* __restrict__ bsum,
                        int* __restrict__ cursor) {
    int idx = blockIdx.x * 1024 + threadIdx.x;
    if (idx < N) {
        int r = rowptr[idx] + bsum[blockIdx.x];
        rowptr[idx] = r;
        cursor[idx] = r;
    }
}

__global__ void k_fill(const void* __restrict__ ei, const int* __restrict__ flags,
                       int E, int N, int* __restrict__ cursor, int* __restrict__ csr_src) {
    int i = blockIdx.x * blockDim.x + threadIdx.x;
    if (i < E) {
        int f = flags[1];
        unsigned d = (unsigned)ldidx(f, ei, (long long)E + i);
        if (d < (unsigned)N) {
            int p = atomicAdd(&cursor[d], 1);
            if ((unsigned)p < (unsigned)E) csr_src[p] = ldidx(f, ei, i);
        }
    }
}

// ---------- layer 0 aggregation: 2 nodes/wave, full-group fast path ----------
__global__ __launch_bounds__(256) void k_l0_agg(
    const int* __restrict__ rowptr, const int* __restrict__ csr_src,
    const float* __restrict__ ssrc, const float* __restrict__ sdst,
    const __hip_bfloat16* __restrict__ h0,
    int N, __hip_bfloat16* __restrict__ skip0_hact) {
    __shared__ ull ews[256];              // 4 waves x (2 nodes x 32 entries)
    int wv = threadIdx.x >> 6, lane = threadIdx.x & 63;
    int half = lane >> 5, l5 = lane & 31;
    int slot = l5 >> 4, c4 = l5 & 15;     // slot 0/1; channels 4*c4..4*c4+3
    int n = blockIdx.x * 8 + wv * 2 + half;
    bool act = n < N;
    int nn = act ? n : 0;
    const uint2* h0w = (const uint2*)h0;
    ull* myw = &ews[wv * 64 + half * 32];

    float sd = sdst[nn];
    float wself = ewgt(ssrc[nn] + sd);

    uint2 selfv = h0w[(size_t)nn * 16 + c4];
    float w0 = (slot == 0) ? wself : 0.f;
    float acc0 = w0 * bflo(selfv.x);
    float acc1 = w0 * bfhi(selfv.x);
    float acc2 = w0 * bflo(selfv.y);
    float acc3 = w0 * bfhi(selfv.y);
    float denp = 0.f;

    int beg = act ? rowptr[nn] : 0;
    int end = act ? rowptr[nn + 1] : 0;
    for (int j0 = beg; j0 < end; j0 += 32) {
        int cnt = end - j0; if (cnt > 32) cnt = 32;
        // weight phase: each of the node's 32 lanes owns one edge
        int s = (l5 < cnt) ? csr_src[j0 + l5] : 0;
        bool v = (l5 < cnt) && ((unsigned)s < (unsigned)N);
        int sg = v ? s : 0;
        float wj = v ? ewgt(ssrc[sg] + sd) : 0.f;
        denp += wj;
        myw[l5] = ((ull)__float_as_uint(wj) << 32) | (unsigned)sg;
        // gather: full 8-edge groups without clamping, then tail
        int k2 = 0;
        int full = cnt & ~7;
        for (; k2 < full; k2 += 8) {
            ull pa = myw[k2 + slot];
            ull pb = myw[k2 + 2 + slot];
            ull pc = myw[k2 + 4 + slot];
            ull pd_ = myw[k2 + 6 + slot];
            float wa = __uint_as_float((unsigned)(pa >> 32));
            float wb = __uint_as_float((unsigned)(pb >> 32));
            float wc = __uint_as_float((unsigned)(pc >> 32));
            float wd = __uint_as_float((unsigned)(pd_ >> 32));
            int sa = (int)(unsigned)(pa & 0xffffffffu);
            int sb = (int)(unsigned)(pb & 0xffffffffu);
            int sc = (int)(unsigned)(pc & 0xffffffffu);
            int sdi = (int)(unsigned)(pd_ & 0xffffffffu);
            uint2 va = h0w[(size_t)sa * 16 + c4];
            uint2 vb = h0w[(size_t)sb * 16 + c4];
            uint2 vc = h0w[(size_t)sc * 16 + c4];
            uint2 vd = h0w[(size_t)sdi * 16 + c4];
            acc0 += wa * bflo(va.x) + wb * bflo(vb.x) + wc * bflo(vc.x) + wd * bflo(vd.x);
            acc1 += wa * bfhi(va.x) + wb * bfhi(vb.x) + wc * bfhi(vc.x) + wd * bfhi(vd.x);
            acc2 += wa * bflo(va.y) + wb * bflo(vb.y) + wc * bflo(vc.y) + wd * bflo(vd.y);
            acc3 += wa * bfhi(va.y) + wb * bfhi(vb.y) + wc * bfhi(vc.y) + wd * bfhi(vd.y);
        }
        for (; k2 < cnt; k2 += 8) {
            int ia = k2 + slot,     ib = k2 + 2 + slot;
            int ic = k2 + 4 + slot, id = k2 + 6 + slot;
            ull pa = myw[ia < cnt ? ia : 0];
            ull pb = myw[ib < cnt ? ib : 0];
            ull pc = myw[ic < cnt ? ic : 0];
            ull pd_ = myw[id < cnt ? id : 0];
            float wa = (ia < cnt) ? __uint_as_float((unsigned)(pa >> 32)) : 0.f;
            float wb = (ib < cnt) ? __uint_as_float((unsigned)(pb >> 32)) : 0.f;
            float wc = (ic < cnt) ? __uint_as_float((unsigned)(pc >> 32)) : 0.f;
            float wd = (id < cnt) ? __uint_as_float((unsigned)(pd_ >> 32)) : 0.f;
            int sa = (int)(unsigned)(pa & 0xffffffffu);
            int sb = (int)(unsigned)(pb & 0xffffffffu);
            int sc = (int)(unsigned)(pc & 0xffffffffu);
            int sdi = (int)(unsigned)(pd_ & 0xffffffffu);
            uint2 va = h0w[(size_t)sa * 16 + c4];
            uint2 vb = h0w[(size_t)sb * 16 + c4];
            uint2 vc = h0w[(size_t)sc * 16 + c4];
            uint2 vd = h0w[(size_t)sdi * 16 + c4];
            acc0 += wa * bflo(va.x) + wb * bflo(vb.x) + wc * bflo(vc.x) + wd * bflo(vd.x);
            acc1 += wa * bfhi(va.x) + wb * bfhi(vb.x) + wc * bfhi(vc.x) + wd * bfhi(vd.x);
            acc2 += wa * bflo(va.y) + wb * bflo(vb.y) + wc * bflo(vc.y) + wd * bflo(vd.y);
            acc3 += wa * bfhi(va.y) + wb * bfhi(vb.y) + wc * bfhi(vc.y) + wd * bfhi(vd.y);
        }
    }
    // combine the 2 slots (xor 16 stays within the 32-lane half)
    acc0 += __shfl_xor(acc0, 16, 64);
    acc1 += __shfl_xor(acc1, 16, 64);
    acc2 += __shfl_xor(acc2, 16, 64);
    acc3 += __shfl_xor(acc3, 16, 64);
    float den = denp;
#pragma unroll
    for (int m = 1; m <= 16; m <<= 1) den += __shfl_xor(den, m, 64);
    den += wself;

    if (slot == 0 && act) {
        uint2 skv = ((const uint2*)skip0_hact)[(size_t)nn * 16 + c4];
        float v0 = sane(acc0 / den + bflo(skv.x));
        float v1 = sane(acc1 / den + bfhi(skv.x));
        float v2 = sane(acc2 / den + bflo(skv.y));
        float v3 = sane(acc3 / den + bfhi(skv.y));
        v0 = v0 > 0.f ? v0 : (__expf(v0) - 1.f);   // ELU
        v1 = v1 > 0.f ? v1 : (__expf(v1) - 1.f);
        v2 = v2 > 0.f ? v2 : (__expf(v2) - 1.f);
        v3 = v3 > 0.f ? v3 : (__expf(v3) - 1.f);
        uint2 o;
        o.x = packbf(v0, v1);
        o.y = packbf(v2, v3);
        ((uint2*)skip0_hact)[(size_t)nn * 16 + c4] = o;
    }
}

// ---------- layer 1 transform: MFMA, Fin=64, C=32 (vectorized staging) ----------
__global__ __launch_bounds__(256) void k_l1(
    const __hip_bfloat16* __restrict__ hact,
    const float* __restrict__ Pf, const __hip_bfloat16* __restrict__ Wg, int N,
    __hip_bfloat16* __restrict__ h1, __hip_bfloat16* __restrict__ skip1,
    float* __restrict__ ssrc, float* __restrict__ sdst) {
    __shared__ __hip_bfloat16 sm[9216];
    __hip_bfloat16* xs  = sm;
    __hip_bfloat16* wt1 = sm + 4608;
    __hip_bfloat16* ws1 = sm + 6912;
    int tid = threadIdx.x;
    int tile = blockIdx.x * 64;

    for (int i = tid * 4; i < 2048; i += 1024) {
        int r = i >> 6, k = i & 63;
        uint2 w0v = *(const uint2*)&Wg[16384 + i];
        uint2 w1v = *(const uint2*)&Wg[18432 + i];
        *(uint2*)&wt1[r * 72 + k] = w0v;
        *(uint2*)&ws1[r * 72 + k] = w1v;
    }
    for (int i = tid * 4; i < 4096; i += 1024) {
        int r = i >> 6, k = i & 63;
        int g = tile + r; if (g >= N) g = N - 1;
        *(uint2*)&xs[r * 72 + k] = *(const uint2*)(hact + (size_t)g * 64 + k);
    }
    __syncthreads();

    int lane = tid & 63, w = tid >> 6;
    int n16 = lane & 15, quad = lane >> 4;
    v4f zf = {0.f, 0.f, 0.f, 0.f};
    v4f acc_h[2], acc_s[2];
#pragma unroll
    for (int t = 0; t < 2; t++) { acc_h[t] = zf; acc_s[t] = zf; }

    int arow = (w << 4) + n16;
#pragma unroll
    for (int s = 0; s < 2; s++) {
        v8s a = ld8(&xs[arow * 72 + s * 32 + (quad << 3)]);
#pragma unroll
        for (int t = 0; t < 2; t++) {
            v8s bh = ld8(&wt1[(t * 16 + n16) * 72 + s * 32 + (quad << 3)]);
            acc_h[t] = __builtin_amdgcn_mfma_f32_16x16x32_bf16(a, bh, acc_h[t], 0, 0, 0);
            v8s bs = ld8(&ws1[(t * 16 + n16) * 72 + s * 32 + (quad << 3)]);
            acc_s[t] = __builtin_amdgcn_mfma_f32_16x16x32_bf16(a, bs, acc_s[t], 0, 0, 0);
        }
    }

    int mbase = tile + (w << 4) + (quad << 2);
    float ps[4] = {0, 0, 0, 0}, pd[4] = {0, 0, 0, 0};
#pragma unroll
    for (int t = 0; t < 2; t++) {
        int ch = t * 16 + n16;
        float av = Pf[192 + ch];
        float dv = Pf[224 + ch];
        float bv = Pf[256 + ch];
#pragma unroll
        for (int r = 0; r < 4; r++) {
            float hv = sane(acc_h[t][r]);
            float sv = sane(acc_s[t][r] + bv);
            int node = mbase + r;
            if (node < N) {
                h1[(size_t)node * 32 + ch] = f2bf(hv);
                skip1[(size_t)node * 32 + ch] = f2bf(sv);
            }
            ps[r] += hv * av;
            pd[r] += hv * dv;
        }
    }
#pragma unroll
    for (int m = 1; m <= 8; m <<= 1) {
#pragma unroll
        for (int r = 0; r < 4; r++) {
            ps[r] += __shfl_xor(ps[r], m, 64);
            pd[r] += __shfl_xor(pd[r], m, 64);
        }
    }
    if (n16 == 0) {
#pragma unroll
        for (int r = 0; r < 4; r++) {
            int node = mbase + r;
            if (node < N) { ssrc[node] = sane(ps[r]); sdst[node] = sane(pd[r]); }
        }
    }
}

// ---------- layer 1 aggregation: 2 nodes/wave, full-group fast path, log_softmax ----------
__global__ __launch_bounds__(256) void k_l1_agg(
    const int* __restrict__ rowptr, const int* __restrict__ csr_src,
    const float* __restrict__ ssrc, const float* __restrict__ sdst,
    const __hip_bfloat16* __restrict__ h1, const __hip_bfloat16* __restrict__ skip1,
    int N, float* __restrict__ out) {
    __shared__ ull ews[256];
    int wv = threadIdx.x >> 6, lane = threadIdx.x & 63;
    int half = lane >> 5, l5 = lane & 31;
    int slot = l5 >> 3, c4 = l5 & 7;      // slot 0..3; channels 4*c4..4*c4+3
    int n = blockIdx.x * 8 + wv * 2 + half;
    bool act = n < N;
    int nn = act ? n : 0;
    const uint2* h1w = (const uint2*)h1;
    ull* myw = &ews[wv * 64 + half * 32];

    float sd = sdst[nn];
    float wself = ewgt(ssrc[nn] + sd);

    uint2 selfv = h1w[(size_t)nn * 8 + c4];
    float w0 = (slot == 0) ? wself : 0.f;
    float acc0 = w0 * bflo(selfv.x);
    float acc1 = w0 * bfhi(selfv.x);
    float acc2 = w0 * bflo(selfv.y);
    float acc3 = w0 * bfhi(selfv.y);
    float denp = 0.f;

    int beg = act ? rowptr[nn] : 0;
    int end = act ? rowptr[nn + 1] : 0;
    for (int j0 = beg; j0 < end; j0 += 32) {
        int cnt = end - j0; if (cnt > 32) cnt = 32;
        int s = (l5 < cnt) ? csr_src[j0 + l5] : 0;
        bool v = (l5 < cnt) && ((unsigned)s < (unsigned)N);
        int sg = v ? s : 0;
        float wj = v ? ewgt(ssrc[sg] + sd) : 0.f;
        denp += wj;
        myw[l5] = ((ull)__float_as_uint(wj) << 32) | (unsigned)sg;
        int k4 = 0;
        int full = cnt & ~15;
        for (; k4 < full; k4 += 16) {
            ull pa = myw[k4 + slot];
            ull pb = myw[k4 + 4 + slot];
            ull pc = myw[k4 + 8 + slot];
            ull pd_ = myw[k4 + 12 + slot];
            float wa = __uint_as_float((unsigned)(pa >> 32));
            float wb = __uint_as_float((unsigned)(pb >> 32));
            float wc = __uint_as_float((unsigned)(pc >> 32));
            float wd = __uint_as_float((unsigned)(pd_ >> 32));
            int sa = (int)(unsigned)(pa & 0xffffffffu);
            int sb = (int)(unsigned)(pb & 0xffffffffu);
            int sc = (int)(unsigned)(pc & 0xffffffffu);
            int sdi = (int)(unsigned)(pd_ & 0xffffffffu);
            uint2 va = h1w[(size_t)sa * 8 + c4];
            uint2 vb = h1w[(size_t)sb * 8 + c4];
            uint2 vc = h1w[(size_t)sc * 8 + c4];
            uint2 vd = h1w[(size_t)sdi * 8 + c4];
            acc0 += wa * bflo(va.x) + wb * bflo(vb.x) + wc * bflo(vc.x) + wd * bflo(vd.x);
            acc1 += wa * bfhi(va.x) + wb * bfhi(vb.x) + wc * bfhi(vc.x) + wd * bfhi(vd.x);
            acc2 += wa * bflo(va.y) + wb * bflo(vb.y) + wc * bflo(vc.y) + wd * bflo(vd.y);
            acc3 += wa * bfhi(va.y) + wb * bfhi(vb.y) + wc * bfhi(vc.y) + wd * bfhi(vd.y);
        }
        for (; k4 < cnt; k4 += 16) {
            int ia = k4 + slot,      ib = k4 + 4 + slot;
            int ic = k4 + 8 + slot,  id = k4 + 12 + slot;
            ull pa = myw[ia < cnt ? ia : 0];
            ull pb = myw[ib < cnt ? ib : 0];
            ull pc = myw[ic < cnt ? ic : 0];
            ull pd_ = myw[id < cnt ? id : 0];
            float wa = (ia < cnt) ? __uint_as_float((unsigned)(pa >> 32)) : 0.f;
            float wb = (ib < cnt) ? __uint_as_float((unsigned)(pb >> 32)) : 0.f;
            float wc = (ic < cnt) ? __uint_as_float((unsigned)(pc >> 32)) : 0.f;
            float wd = (id < cnt) ? __uint_as_float((unsigned)(pd_ >> 32)) : 0.f;
            int sa = (int)(unsigned)(pa & 0xffffffffu);
            int sb = (int)(unsigned)(pb & 0xffffffffu);
            int sc = (int)(unsigned)(pc & 0xffffffffu);
            int sdi = (int)(unsigned)(pd_ & 0xffffffffu);
            uint2 va = h1w[(size_t)sa * 8 + c4];
            uint2 vb = h1w[(size_t)sb * 8 + c4];
            uint2 vc = h1w[(size_t)sc * 8 + c4];
            uint2 vd = h1w[(size_t)sdi * 8 + c4];
            acc0 += wa * bflo(va.x) + wb * bflo(vb.x) + wc * bflo(vc.x) + wd * bflo(vd.x);
            acc1 += wa * bfhi(va.x) + wb * bfhi(vb.x) + wc * bfhi(vc.x) + wd * bfhi(vd.x);
            acc2 += wa * bflo(va.y) + wb * bflo(vb.y) + wc * bflo(vc.y) + wd * bflo(vd.y);
            acc3 += wa * bfhi(va.y) + wb * bfhi(vb.y) + wc * bfhi(vc.y) + wd * bfhi(vd.y);
        }
    }
    acc0 += __shfl_xor(acc0, 8, 64); acc0 += __shfl_xor(acc0, 16, 64);
    acc1 += __shfl_xor(acc1, 8, 64); acc1 += __shfl_xor(acc1, 16, 64);
    acc2 += __shfl_xor(acc2, 8, 64); acc2 += __shfl_xor(acc2, 16, 64);
    acc3 += __shfl_xor(acc3, 8, 64); acc3 += __shfl_xor(acc3, 16, 64);
    float den = denp;
#pragma unroll
    for (int m = 1; m <= 16; m <<= 1) den += __shfl_xor(den, m, 64);
    den += wself;

    uint2 skv = ((const uint2*)skip1)[(size_t)nn * 8 + c4];
    float o0 = sane(acc0 / den + bflo(skv.x));
    float o1 = sane(acc1 / den + bfhi(skv.x));
    float o2 = sane(acc2 / den + bflo(skv.y));
    float o3 = sane(acc3 / den + bfhi(skv.y));
    float m = fmaxf(fmaxf(o0, o1), fmaxf(o2, o3));
#pragma unroll
    for (int k = 1; k <= 4; k <<= 1) m = fmaxf(m, __shfl_xor(m, k, 64));
    float ex = __expf(o0 - m) + __expf(o1 - m) + __expf(o2 - m) + __expf(o3 - m);
#pragma unroll
    for (int k = 1; k <= 4; k <<= 1) ex += __shfl_xor(ex, k, 64);
    float l = __logf(ex);
    float r0 = o0 - m - l, r1 = o1 - m - l, r2 = o2 - m - l, r3 = o3 - m - l;
    if (!isfinite(r0)) r0 = 0.f;
    if (!isfinite(r1)) r1 = 0.f;
    if (!isfinite(r2)) r2 = 0.f;
    if (!isfinite(r3)) r3 = 0.f;
    if (slot == 0 && act) {
        float4 o4; o4.x = r0; o4.y = r1; o4.z = r2; o4.w = r3;
        *(float4*)&out[(size_t)nn * 32 + 4 * c4] = o4;
    }
}

__global__ void k_sentinel(float* __restrict__ out, int n, float val) {
    int i = blockIdx.x * blockDim.x + threadIdx.x;
    if (i < n) out[i] = val;
}

extern "C" void kernel_launch(void* const* d_in, const int* in_sizes, int n_in,
                              void* d_out, int out_size, void* d_ws, size_t ws_size,
                              hipStream_t stream) {
    const void* x  = d_in[0];
    const void* ei = d_in[1];
    float* out = (float*)d_out;

    int N = in_sizes[0] / 128;
    int E = in_sizes[1] / 2;

    int NB  = (N + BR - 1) >> BSHIFT;
    int gch = (E + CHUNK - 1) / CHUNK;
    if (gch < 1) gch = 1;
    int Lb = (N + 63) / 64;
    bool fast = (N <= (NBMAX << BSHIFT)) && ((size_t)E * 4 <= (size_t)N * 128);

    char* ws = (char*)d_ws;
    size_t off = 0;
    auto alloc = [&](size_t bytes) -> char* {
        char* p = ws + off;
        off += (bytes + 255) & ~(size_t)255;
        return p;
    };
    int*   flags   = (int*)alloc(2 * 4);
    float* Pf      = (float*)alloc(288 * 4);
    __hip_bfloat16* Wg = (__hip_bfloat16*)alloc(20480 * 2);
    int*   rowptr  = (int*)alloc((size_t)(N + 1) * 4);
    int*   cursor  = (int*)alloc((size_t)N * 4);          // -> ssrc overlay after CSR
    float* sdst01  = (float*)alloc((size_t)N * 4);
    int*   bsum    = (int*)alloc(1024 * 4);
    int*   bcount  = (int*)alloc(NBMAX * 4);
    int*   bbase   = (int*)alloc((NBMAX + 1) * 4);
    int*   csr_src = (int*)alloc((size_t)E * 4);
    unsigned* binned = (unsigned*)alloc(fast ? (size_t)E * 4 : 0);
    int*   hist    = (int*)alloc(fast ? (size_t)gch * NB * 4 : 0);
    int*   cb      = (int*)alloc(fast ? (size_t)gch * NB * 4 : 0);
    __hip_bfloat16* h0    = (__hip_bfloat16*)alloc((size_t)N * 64 * 2); // -> h1+skip1 after agg
    __hip_bfloat16* skip0 = (__hip_bfloat16*)alloc((size_t)N * 64 * 2); // -> hact in place
    size_t required = off;

    if (ws_size < required) {
        float mb = (float)(double)(ws_size >> 20);
        k_sentinel<<<(out_size + 255) / 256, 256, 0, stream>>>(out, out_size, mb);
        return;
    }

    float* ssrc01 = (float*)cursor;
    __hip_bfloat16* h1    = h0;
    __hip_bfloat16* skip1 = h0 + (size_t)N * 32;

    k_probe<<<1, 256, 0, stream>>>((const unsigned*)x, N * 64, (const unsigned*)ei, flags);
    k_params<<<40, 256, 0, stream>>>(flags, d_in[2], d_in[6], d_in[3], d_in[4],
                                     d_in[5], d_in[7], d_in[8], d_in[12],
                                     d_in[9], d_in[10], d_in[11], d_in[13], Pf, Wg);

    if (fast) {
        // merged: blocks [0,gch) do chunk histogram; blocks [gch,gch+Lb) do layer-0 transform
        k1_chist_l0<<<gch + Lb, 256, 0, stream>>>(ei, x, flags, Pf, Wg, N, E, NB, gch,
                                                  hist, h0, skip0, ssrc01, sdst01);
        k_cscan<<<NB, 1024, 0, stream>>>(hist, gch, NB, cb, bcount);
        k_bscan<<<1, NBMAX, 0, stream>>>(bcount, NB, bbase);
        k_bscatter<<<gch, 256, 0, stream>>>(ei, flags, E, N, NB, bbase, cb, binned);
        k_bbuild<<<NB, 256, 0, stream>>>(binned, bbase, N, NB, rowptr, csr_src);
    } else {
        int B = (N + 1023) / 1024;
        k_zero<<<(N + 255) / 256, 256, 0, stream>>>(cursor, N);
        k_deg<<<(E + 255) / 256, 256, 0, stream>>>(ei, flags, E, N, cursor);
        k_scan1<<<B, 1024, 0, stream>>>(cursor, N, rowptr, bsum);
        k_scan2<<<1, 1024, 0, stream>>>(bsum, B, rowptr, N);
        k_scan3<<<B, 1024, 0, stream>>>(N, rowptr, bsum, cursor);
        k_fill<<<(E + 255) / 256, 256, 0, stream>>>(ei, flags, E, N, cursor, csr_src);
        k1_chist_l0<<<Lb, 256, 0, stream>>>(ei, x, flags, Pf, Wg, N, E, NB, 0,
                                            bsum, h0, skip0, ssrc01, sdst01);
    }

    k_l0_agg<<<(N + 7) / 8, 256, 0, stream>>>(rowptr, csr_src, ssrc01, sdst01,
                                              h0, N, skip0);
    k_l1<<<(N + 63) / 64, 256, 0, stream>>>(skip0, Pf, Wg, N,
                                            h1, skip1, ssrc01, sdst01);
    k_l1_agg<<<(N + 7) / 8, 256, 0, stream>>>(rowptr, csr_src, ssrc01, sdst01,
                                              h1, skip1, N, out);
}

// Round 11
// 268.342 us; speedup vs baseline: 1.1987x; 1.0350x over previous
//
#include <hip/hip_runtime.h>
#include <hip/hip_bf16.h>
#include <math.h>

#define NEG_SLOPE 0.2f
#define ECLAMP 30.0f
#define HCLAMP 1.0e4f

#define BSHIFT 8
#define BR 256
#define NBMAX 1024
#define CHUNK 2048

typedef short v8s __attribute__((ext_vector_type(8)));
typedef float v4f __attribute__((ext_vector_type(4)));
typedef unsigned long long ull;

__device__ __forceinline__ float bf2f(__hip_bfloat16 v) { return __bfloat162float(v); }
__device__ __forceinline__ __hip_bfloat16 f2bf(float v) { return __float2bfloat16(v); }
__device__ __forceinline__ float sane(float v)   { return fminf(fmaxf(v, -HCLAMP), HCLAMP); }
__device__ __forceinline__ float eclampf(float v){ return fminf(fmaxf(v, -ECLAMP), ECLAMP); }

__device__ __forceinline__ float ldany(int isf32, const void* p, int i) {
    return isf32 ? ((const float*)p)[i] : bf2f(((const __hip_bfloat16*)p)[i]);
}
__device__ __forceinline__ int ldidx(int is64, const void* p, long long i) {
    return is64 ? (int)((const long long*)p)[i] : ((const int*)p)[i];
}
__device__ __forceinline__ v8s ld8(const __hip_bfloat16* p) { return *(const v8s*)p; }

// leaky_relu + clamp + exp
__device__ __forceinline__ float ewgt(float e) {
    e = e > 0.f ? e : NEG_SLOPE * e;
    return __expf(eclampf(e));
}

__device__ __forceinline__ float bflo(unsigned v) { return __uint_as_float(v << 16); }
__device__ __forceinline__ float bfhi(unsigned v) { return __uint_as_float(v & 0xffff0000u); }
__device__ __forceinline__ unsigned packbf(float a, float b) {
    __hip_bfloat16 x = f2bf(a), y = f2bf(b);
    return (unsigned)(*(unsigned short*)&x) | ((unsigned)(*(unsigned short*)&y) << 16);
}

// ---------- dtype probe ----------
__global__ void k_probe(const unsigned* __restrict__ xw, int nw_safe,
                        const unsigned* __restrict__ ew, int* __restrict__ flags) {
    __shared__ int cnt[2];
    int t = threadIdx.x;
    if (t < 2) cnt[t] = 0;
    __syncthreads();
    unsigned w = xw[(unsigned)(t * 9973) % (unsigned)nw_safe];
    unsigned lo = w & 0xffffu;
    unsigned exp = (lo >> 7) & 0xffu;
    if (lo != 0u && (exp < 90u || exp > 160u)) atomicAdd(&cnt[0], 1);
    if (ew[2 * t + 1] == 0u) atomicAdd(&cnt[1], 1);
    __syncthreads();
    if (t == 0) { flags[0] = (2 * cnt[0] > 256) ? 1 : 0; flags[1] = (cnt[1] >= 200) ? 1 : 0; }
}

// ---------- params: Pf fp32 vectors + transposed bf16 weights ----------
__global__ void k_params(const int* __restrict__ flags,
                         const void* W0, const void* sW0, const void* as0, const void* ad0,
                         const void* b0, const void* sb0, const void* W1, const void* sW1,
                         const void* as1, const void* ad1, const void* b1, const void* sb1,
                         float* __restrict__ Pf, __hip_bfloat16* __restrict__ Wg) {
    int f = flags[0];
    int t = blockIdx.x * blockDim.x + threadIdx.x;
    int T = gridDim.x * blockDim.x;
    for (int i = t; i < 8192; i += T) {
        int n = i >> 7, k = i & 127;
        Wg[i]        = f2bf(ldany(f, W0,  k * 64 + n));
        Wg[8192 + i] = f2bf(ldany(f, sW0, k * 64 + n));
    }
    for (int i = t; i < 2048; i += T) {
        int n = i >> 6, k = i & 63;
        Wg[16384 + i] = f2bf(ldany(f, W1,  k * 32 + n));
        Wg[18432 + i] = f2bf(ldany(f, sW1, k * 32 + n));
    }
    if (t < 64) {
        Pf[t]       = ldany(f, as0, t);
        Pf[64 + t]  = ldany(f, ad0, t);
        Pf[128 + t] = ldany(f, b0, t) + ldany(f, sb0, t);
    }
    if (t < 32) {
        Pf[192 + t] = ldany(f, as1, t);
        Pf[224 + t] = ldany(f, ad1, t);
        Pf[256 + t] = ldany(f, b1, t) + ldany(f, sb1, t);
    }
}

__global__ void k_zero(int* __restrict__ p, int n) {
    int i = blockIdx.x * blockDim.x + threadIdx.x;
    if (i < n) p[i] = 0;
}

// ================= fast CSR build: deterministic bucket sort (no global atomics) =================
__global__ __launch_bounds__(256) void k_chist(const void* __restrict__ ei,
                                               const int* __restrict__ flags,
                                               int E, int N, int NB,
                                               int* __restrict__ hist) {
    __shared__ int h[NBMAX];
    for (int i = threadIdx.x; i < NB; i += 256) h[i] = 0;
    __syncthreads();
    int f = flags[1];
    long long c0 = (long long)blockIdx.x * CHUNK;
    long long c1 = c0 + CHUNK;
    if (c1 > E) c1 = E;
    for (long long i = c0 + threadIdx.x; i < c1; i += 256) {
        unsigned d = (unsigned)ldidx(f, ei, (long long)E + i);
        if (d < (unsigned)N) atomicAdd(&h[d >> BSHIFT], 1);
    }
    __syncthreads();
    long long base = (long long)blockIdx.x * NB;
    for (int i = threadIdx.x; i < NB; i += 256) hist[base + i] = h[i];
}

__global__ __launch_bounds__(1024) void k_cscan(const int* __restrict__ hist,
                                                int gch, int NB,
                                                int* __restrict__ cb,
                                                int* __restrict__ bcount) {
    __shared__ int sh[1024];
    int b = blockIdx.x;
    int t = threadIdx.x;
    int run = 0;
    for (int base = 0; base < gch; base += 1024) {
        int c = base + t;
        int v = (c < gch) ? hist[(long long)c * NB + b] : 0;
        sh[t] = v;
        __syncthreads();
        for (int off = 1; off < 1024; off <<= 1) {
            int xv = (t >= off) ? sh[t - off] : 0;
            __syncthreads();
            sh[t] += xv;
            __syncthreads();
        }
        if (c < gch) cb[(long long)c * NB + b] = run + sh[t] - v;
        run += sh[1023];
        __syncthreads();
    }
    if (t == 0) bcount[b] = run;
}

__global__ void k_bscan(const int* __restrict__ bcount, int NB,
                        int* __restrict__ bbase) {
    __shared__ int sh[NBMAX];
    int t = threadIdx.x;
    int v = (t < NB) ? bcount[t] : 0;
    sh[t] = v;
    __syncthreads();
    for (int off = 1; off < NBMAX; off <<= 1) {
        int xv = (t >= off) ? sh[t - off] : 0;
        __syncthreads();
        sh[t] += xv;
        __syncthreads();
    }
    if (t < NB) bbase[t] = sh[t] - v;
    if (t == NB - 1) bbase[NB] = sh[t];
}

__global__ __launch_bounds__(256) void k_bscatter(const void* __restrict__ ei,
                                                  const int* __restrict__ flags,
                                                  int E, int N, int NB,
                                                  const int* __restrict__ bbase,
                                                  const int* __restrict__ cb,
                                                  unsigned* __restrict__ binned) {
    __shared__ int rb[NBMAX];
    int f = flags[1];
    long long cbase = (long long)blockIdx.x * NB;
    for (int i = threadIdx.x; i < NB; i += 256) rb[i] = bbase[i] + cb[cbase + i];
    __syncthreads();
    long long c0 = (long long)blockIdx.x * CHUNK;
    long long c1 = c0 + CHUNK;
    if (c1 > E) c1 = E;
    for (long long i = c0 + threadIdx.x; i < c1; i += 256) {
        unsigned d = (unsigned)ldidx(f, ei, (long long)E + i);
        if (d < (unsigned)N) {
            int b = d >> BSHIFT;
            unsigned s = (unsigned)ldidx(f, ei, i);
            if (s >= (unsigned)N) s = 0x00FFFFFFu;  // agg guard drops it (N < 2^24)
            int r = atomicAdd(&rb[b], 1);
            binned[r] = ((d & (unsigned)(BR - 1)) << 24) | s;
        }
    }
}

__global__ __launch_bounds__(256) void k_bbuild(const unsigned* __restrict__ binned,
                                                const int* __restrict__ bbase,
                                                int N, int NB,
                                                int* __restrict__ rowptr,
                                                int* __restrict__ csr_src) {
    __shared__ int ldeg[BR];
    __shared__ int lpos[BR];
    int b = blockIdx.x;
    int t = threadIdx.x;
    int e0 = bbase[b], e1 = bbase[b + 1];
    ldeg[t] = 0;
    __syncthreads();
    for (int i = e0 + t; i < e1; i += 256) {
        atomicAdd(&ldeg[binned[i] >> 24], 1);
    }
    __syncthreads();
    int v = ldeg[t];
    lpos[t] = v;
    __syncthreads();
    for (int off = 1; off < BR; off <<= 1) {
        int xv = (t >= off) ? lpos[t - off] : 0;
        __syncthreads();
        lpos[t] += xv;
        __syncthreads();
    }
    int excl = lpos[t] - v;
    int node = (b << BSHIFT) + t;
    if (node < N) rowptr[node] = e0 + excl;
    if (b == NB - 1 && t == 0) rowptr[N] = e1;
    ldeg[t] = e0 + excl;   // reuse as cursor
    __syncthreads();
    for (int i = e0 + t; i < e1; i += 256) {
        unsigned w = binned[i];
        int p = atomicAdd(&ldeg[w >> 24], 1);
        csr_src[p] = (int)(w & 0x00FFFFFFu);
    }
}

// ================= fallback CSR build (old path, N > 262144) =================
__global__ void k_deg(const void* __restrict__ ei, const int* __restrict__ flags,
                      int E, int N, int* __restrict__ deg) {
    int i = blockIdx.x * blockDim.x + threadIdx.x;
    if (i < E) {
        unsigned d = (unsigned)ldidx(flags[1], ei, (long long)E + i);
        if (d < (unsigned)N) atomicAdd(&deg[d], 1);
    }
}

__global__ void k_scan1(const int* __restrict__ deg, int N,
                        int* __restrict__ rowptr, int* __restrict__ bsum) {
    __shared__ int sh[1024];
    int t = threadIdx.x;
    int idx = blockIdx.x * 1024 + t;
    int v = (idx < N) ? deg[idx] : 0;
    sh[t] = v;
    __syncthreads();
    for (int off = 1; off < 1024; off <<= 1) {
        int xv = (t >= off) ? sh[t - off] : 0;
        __syncthreads();
        sh[t] += xv;
        __syncthreads();
    }
    if (idx < N) rowptr[idx] = sh[t] - v;
    if (t == 1023) bsum[blockIdx.x] = sh[1023];
}

__global__ void k_scan2(int* __restrict__ bsum, int B, int* __restrict__ rowptr, int N) {
    __shared__ int sh[1024];
    int t = threadIdx.x;
    int v = (t < B) ? bsum[t] : 0;
    sh[t] = v;
    __syncthreads();
    for (int off = 1; off < 1024; off <<= 1) {
        int xv = (t >= off) ? sh[t - off] : 0;
        __syncthreads();
        sh[t] += xv;
        __syncthreads();
    }
    if (t < B) bsum[t] = sh[t] - v;
    if (t == 1023) rowptr[N] = sh[1023];
}

__global__ void k_scan3(int N, int* __restrict__ rowptr, const int* __restrict__ bsum,
                        int* __restrict__ cursor) {
    int idx = blockIdx.x * 1024 + threadIdx.x;
    if (idx < N) {
        int r = rowptr[idx] + bsum[blockIdx.x];
        rowptr[idx] = r;
        cursor[idx] = r;
    }
}

__global__ void k_fill(const void* __restrict__ ei, const int* __restrict__ flags,
                       int E, int N, int* __restrict__ cursor, int* __restrict__ csr_src) {
    int i = blockIdx.x * blockDim.x + threadIdx.x;
    if (i < E) {
        int f = flags[1];
        unsigned d = (unsigned)ldidx(f, ei, (long long)E + i);
        if (d < (unsigned)N) {
            int p = atomicAdd(&cursor[d], 1);
            if ((unsigned)p < (unsigned)E) csr_src[p] = ldidx(f, ei, i);
        }
    }
}

// ---------- layer 0 transform: MFMA 16x16x32 bf16 (vectorized staging) ----------
__global__ __launch_bounds__(256) void k_l0(
    const void* __restrict__ x, const int* __restrict__ flags,
    const float* __restrict__ Pf, const __hip_bfloat16* __restrict__ Wg, int N,
    __hip_bfloat16* __restrict__ h0, __hip_bfloat16* __restrict__ skip0,
    float* __restrict__ ssrc, float* __restrict__ sdst) {
    __shared__ __hip_bfloat16 sm[26112];
    __hip_bfloat16* xs  = sm;
    __hip_bfloat16* wt0 = sm + 8704;
    __hip_bfloat16* wts = sm + 17408;
    int tid = threadIdx.x;
    int f = flags[0];
    int tile = blockIdx.x * 64;

    for (int i = tid * 4; i < 8192; i += 1024) {
        int r = i >> 7, k = i & 127;
        uint2 w0v = *(const uint2*)&Wg[i];
        uint2 w1v = *(const uint2*)&Wg[8192 + i];
        *(uint2*)&wt0[r * 136 + k] = w0v;
        *(uint2*)&wts[r * 136 + k] = w1v;
    }
    for (int i = tid * 4; i < 8192; i += 1024) {
        int r = i >> 7, k = i & 127;
        int g = tile + r; if (g >= N) g = N - 1;
        uint2* dx = (uint2*)&xs[r * 136 + k];
        if (f) {
            float4 v = *(const float4*)((const float*)x + (size_t)g * 128 + k);
            uint2 o; o.x = packbf(v.x, v.y); o.y = packbf(v.z, v.w);
            *dx = o;
        } else {
            *dx = *(const uint2*)((const __hip_bfloat16*)x + (size_t)g * 128 + k);
        }
    }
    __syncthreads();

    int lane = tid & 63, w = tid >> 6;
    int n16 = lane & 15, quad = lane >> 4;
    v4f zf = {0.f, 0.f, 0.f, 0.f};
    v4f acc_h[4], acc_s[4];
#pragma unroll
    for (int t = 0; t < 4; t++) { acc_h[t] = zf; acc_s[t] = zf; }

    int arow = (w << 4) + n16;
#pragma unroll
    for (int s = 0; s < 4; s++) {
        v8s a = ld8(&xs[arow * 136 + s * 32 + (quad << 3)]);
#pragma unroll
        for (int t = 0; t < 4; t++) {
            v8s bh = ld8(&wt0[(t * 16 + n16) * 136 + s * 32 + (quad << 3)]);
            acc_h[t] = __builtin_amdgcn_mfma_f32_16x16x32_bf16(a, bh, acc_h[t], 0, 0, 0);
            v8s bs = ld8(&wts[(t * 16 + n16) * 136 + s * 32 + (quad << 3)]);
            acc_s[t] = __builtin_amdgcn_mfma_f32_16x16x32_bf16(a, bs, acc_s[t], 0, 0, 0);
        }
    }

    int mbase = tile + (w << 4) + (quad << 2);
    float ps[4] = {0, 0, 0, 0}, pd[4] = {0, 0, 0, 0};
#pragma unroll
    for (int t = 0; t < 4; t++) {
        int ch = t * 16 + n16;
        float av = Pf[ch];
        float dv = Pf[64 + ch];
        float bv = Pf[128 + ch];
#pragma unroll
        for (int r = 0; r < 4; r++) {
            float hv = sane(acc_h[t][r]);
            float sv = sane(acc_s[t][r] + bv);
            int node = mbase + r;
            if (node < N) {
                h0[(size_t)node * 64 + ch] = f2bf(hv);
                skip0[(size_t)node * 64 + ch] = f2bf(sv);
            }
            ps[r] += hv * av;
            pd[r] += hv * dv;
        }
    }
#pragma unroll
    for (int m = 1; m <= 8; m <<= 1) {
#pragma unroll
        for (int r = 0; r < 4; r++) {
            ps[r] += __shfl_xor(ps[r], m, 64);
            pd[r] += __shfl_xor(pd[r], m, 64);
        }
    }
    if (n16 == 0) {
#pragma unroll
        for (int r = 0; r < 4; r++) {
            int node = mbase + r;
            if (node < N) { ssrc[node] = sane(ps[r]); sdst[node] = sane(pd[r]); }
        }
    }
}

// ---------- layer 0 aggregation: 2 nodes/wave, full-group fast path ----------
__global__ __launch_bounds__(256) void k_l0_agg(
    const int* __restrict__ rowptr, const int* __restrict__ csr_src,
    const float* __restrict__ ssrc, const float* __restrict__ sdst,
    const __hip_bfloat16* __restrict__ h0,
    int N, __hip_bfloat16* __restrict__ skip0_hact) {
    __shared__ ull ews[256];              // 4 waves x (2 nodes x 32 entries)
    int wv = threadIdx.x >> 6, lane = threadIdx.x & 63;
    int half = lane >> 5, l5 = lane & 31;
    int slot = l5 >> 4, c4 = l5 & 15;     // slot 0/1; channels 4*c4..4*c4+3
    int n = blockIdx.x * 8 + wv * 2 + half;
    bool act = n < N;
    int nn = act ? n : 0;
    const uint2* h0w = (const uint2*)h0;
    ull* myw = &ews[wv * 64 + half * 32];

    float sd = sdst[nn];
    float wself = ewgt(ssrc[nn] + sd);

    uint2 selfv = h0w[(size_t)nn * 16 + c4];
    float w0 = (slot == 0) ? wself : 0.f;
    float acc0 = w0 * bflo(selfv.x);
    float acc1 = w0 * bfhi(selfv.x);
    float acc2 = w0 * bflo(selfv.y);
    float acc3 = w0 * bfhi(selfv.y);
    float denp = 0.f;

    int beg = act ? rowptr[nn] : 0;
    int end = act ? rowptr[nn + 1] : 0;
    for (int j0 = beg; j0 < end; j0 += 32) {
        int cnt = end - j0; if (cnt > 32) cnt = 32;
        // weight phase: each of the node's 32 lanes owns one edge
        int s = (l5 < cnt) ? csr_src[j0 + l5] : 0;
        bool v = (l5 < cnt) && ((unsigned)s < (unsigned)N);
        int sg = v ? s : 0;
        float wj = v ? ewgt(ssrc[sg] + sd) : 0.f;
        denp += wj;
        myw[l5] = ((ull)__float_as_uint(wj) << 32) | (unsigned)sg;
        // gather: full 8-edge groups without clamping, then tail
        int k2 = 0;
        int full = cnt & ~7;
        for (; k2 < full; k2 += 8) {
            ull pa = myw[k2 + slot];
            ull pb = myw[k2 + 2 + slot];
            ull pc = myw[k2 + 4 + slot];
            ull pd_ = myw[k2 + 6 + slot];
            float wa = __uint_as_float((unsigned)(pa >> 32));
            float wb = __uint_as_float((unsigned)(pb >> 32));
            float wc = __uint_as_float((unsigned)(pc >> 32));
            float wd = __uint_as_float((unsigned)(pd_ >> 32));
            int sa = (int)(unsigned)(pa & 0xffffffffu);
            int sb = (int)(unsigned)(pb & 0xffffffffu);
            int sc = (int)(unsigned)(pc & 0xffffffffu);
            int sdi = (int)(unsigned)(pd_ & 0xffffffffu);
            uint2 va = h0w[(size_t)sa * 16 + c4];
            uint2 vb = h0w[(size_t)sb * 16 + c4];
            uint2 vc = h0w[(size_t)sc * 16 + c4];
            uint2 vd = h0w[(size_t)sdi * 16 + c4];
            acc0 += wa * bflo(va.x) + wb * bflo(vb.x) + wc * bflo(vc.x) + wd * bflo(vd.x);
            acc1 += wa * bfhi(va.x) + wb * bfhi(vb.x) + wc * bfhi(vc.x) + wd * bfhi(vd.x);
            acc2 += wa * bflo(va.y) + wb * bflo(vb.y) + wc * bflo(vc.y) + wd * bflo(vd.y);
            acc3 += wa * bfhi(va.y) + wb * bfhi(vb.y) + wc * bfhi(vc.y) + wd * bfhi(vd.y);
        }
        for (; k2 < cnt; k2 += 8) {
            int ia = k2 + slot,     ib = k2 + 2 + slot;
            int ic = k2 + 4 + slot, id = k2 + 6 + slot;
            ull pa = myw[ia < cnt ? ia : 0];
            ull pb = myw[ib < cnt ? ib : 0];
            ull pc = myw[ic < cnt ? ic : 0];
            ull pd_ = myw[id < cnt ? id : 0];
            float wa = (ia < cnt) ? __uint_as_float((unsigned)(pa >> 32)) : 0.f;
            float wb = (ib < cnt) ? __uint_as_float((unsigned)(pb >> 32)) : 0.f;
            float wc = (ic < cnt) ? __uint_as_float((unsigned)(pc >> 32)) : 0.f;
            float wd = (id < cnt) ? __uint_as_float((unsigned)(pd_ >> 32)) : 0.f;
            int sa = (int)(unsigned)(pa & 0xffffffffu);
            int sb = (int)(unsigned)(pb & 0xffffffffu);
            int sc = (int)(unsigned)(pc & 0xffffffffu);
            int sdi = (int)(unsigned)(pd_ & 0xffffffffu);
            uint2 va = h0w[(size_t)sa * 16 + c4];
            uint2 vb = h0w[(size_t)sb * 16 + c4];
            uint2 vc = h0w[(size_t)sc * 16 + c4];
            uint2 vd = h0w[(size_t)sdi * 16 + c4];
            acc0 += wa * bflo(va.x) + wb * bflo(vb.x) + wc * bflo(vc.x) + wd * bflo(vd.x);
            acc1 += wa * bfhi(va.x) + wb * bfhi(vb.x) + wc * bfhi(vc.x) + wd * bfhi(vd.x);
            acc2 += wa * bflo(va.y) + wb * bflo(vb.y) + wc * bflo(vc.y) + wd * bflo(vd.y);
            acc3 += wa * bfhi(va.y) + wb * bfhi(vb.y) + wc * bfhi(vc.y) + wd * bfhi(vd.y);
        }
    }
    // combine the 2 slots (xor 16 stays within the 32-lane half)
    acc0 += __shfl_xor(acc0, 16, 64);
    acc1 += __shfl_xor(acc1, 16, 64);
    acc2 += __shfl_xor(acc2, 16, 64);
    acc3 += __shfl_xor(acc3, 16, 64);
    float den = denp;
#pragma unroll
    for (int m = 1; m <= 16; m <<= 1) den += __shfl_xor(den, m, 64);
    den += wself;

    if (slot == 0 && act) {
        uint2 skv = ((const uint2*)skip0_hact)[(size_t)nn * 16 + c4];
        float v0 = sane(acc0 / den + bflo(skv.x));
        float v1 = sane(acc1 / den + bfhi(skv.x));
        float v2 = sane(acc2 / den + bflo(skv.y));
        float v3 = sane(acc3 / den + bfhi(skv.y));
        v0 = v0 > 0.f ? v0 : (__expf(v0) - 1.f);   // ELU
        v1 = v1 > 0.f ? v1 : (__expf(v1) - 1.f);
        v2 = v2 > 0.f ? v2 : (__expf(v2) - 1.f);
        v3 = v3 > 0.f ? v3 : (__expf(v3) - 1.f);
        uint2 o;
        o.x = packbf(v0, v1);
        o.y = packbf(v2, v3);
        ((uint2*)skip0_hact)[(size_t)nn * 16 + c4] = o;
    }
}

// ---------- layer 1 transform: MFMA, Fin=64, C=32 (vectorized staging) ----------
__global__ __launch_bounds__(256) void k_l1(
    const __hip_bfloat16* __restrict__ hact,
    const float* __restrict__ Pf, const __hip_bfloat16* __restrict__ Wg, int N,
    __hip_bfloat16* __restrict__ h1, __hip_bfloat16* __restrict__ skip1,
    float* __restrict__ ssrc, float* __restrict__ sdst) {
    __shared__ __hip_bfloat16 sm[9216];
    __hip_bfloat16* xs  = sm;
    __hip_bfloat16* wt1 = sm + 4608;
    __hip_bfloat16* ws1 = sm + 6912;
    int tid = threadIdx.x;
    int tile = blockIdx.x * 64;

    for (int i = tid * 4; i < 2048; i += 1024) {
        int r = i >> 6, k = i & 63;
        uint2 w0v = *(const uint2*)&Wg[16384 + i];
        uint2 w1v = *(const uint2*)&Wg[18432 + i];
        *(uint2*)&wt1[r * 72 + k] = w0v;
        *(uint2*)&ws1[r * 72 + k] = w1v;
    }
    for (int i = tid * 4; i < 4096; i += 1024) {
        int r = i >> 6, k = i & 63;
        int g = tile + r; if (g >= N) g = N - 1;
        *(uint2*)&xs[r * 72 + k] = *(const uint2*)(hact + (size_t)g * 64 + k);
    }
    __syncthreads();

    int lane = tid & 63, w = tid >> 6;
    int n16 = lane & 15, quad = lane >> 4;
    v4f zf = {0.f, 0.f, 0.f, 0.f};
    v4f acc_h[2], acc_s[2];
#pragma unroll
    for (int t = 0; t < 2; t++) { acc_h[t] = zf; acc_s[t] = zf; }

    int arow = (w << 4) + n16;
#pragma unroll
    for (int s = 0; s < 2; s++) {
        v8s a = ld8(&xs[arow * 72 + s * 32 + (quad << 3)]);
#pragma unroll
        for (int t = 0; t < 2; t++) {
            v8s bh = ld8(&wt1[(t * 16 + n16) * 72 + s * 32 + (quad << 3)]);
            acc_h[t] = __builtin_amdgcn_mfma_f32_16x16x32_bf16(a, bh, acc_h[t], 0, 0, 0);
            v8s bs = ld8(&ws1[(t * 16 + n16) * 72 + s * 32 + (quad << 3)]);
            acc_s[t] = __builtin_amdgcn_mfma_f32_16x16x32_bf16(a, bs, acc_s[t], 0, 0, 0);
        }
    }

    int mbase = tile + (w << 4) + (quad << 2);
    float ps[4] = {0, 0, 0, 0}, pd[4] = {0, 0, 0, 0};
#pragma unroll
    for (int t = 0; t < 2; t++) {
        int ch = t * 16 + n16;
        float av = Pf[192 + ch];
        float dv = Pf[224 + ch];
        float bv = Pf[256 + ch];
#pragma unroll
        for (int r = 0; r < 4; r++) {
            float hv = sane(acc_h[t][r]);
            float sv = sane(acc_s[t][r] + bv);
            int node = mbase + r;
            if (node < N) {
                h1[(size_t)node * 32 + ch] = f2bf(hv);
                skip1[(size_t)node * 32 + ch] = f2bf(sv);
            }
            ps[r] += hv * av;
            pd[r] += hv * dv;
        }
    }
#pragma unroll
    for (int m = 1; m <= 8; m <<= 1) {
#pragma unroll
        for (int r = 0; r < 4; r++) {
            ps[r] += __shfl_xor(ps[r], m, 64);
            pd[r] += __shfl_xor(pd[r], m, 64);
        }
    }
    if (n16 == 0) {
#pragma unroll
        for (int r = 0; r < 4; r++) {
            int node = mbase + r;
            if (node < N) { ssrc[node] = sane(ps[r]); sdst[node] = sane(pd[r]); }
        }
    }
}

// ---------- layer 1 aggregation: 2 nodes/wave, full-group fast path, log_softmax ----------
__global__ __launch_bounds__(256) void k_l1_agg(
    const int* __restrict__ rowptr, const int* __restrict__ csr_src,
    const float* __restrict__ ssrc, const float* __restrict__ sdst,
    const __hip_bfloat16* __restrict__ h1, const __hip_bfloat16* __restrict__ skip1,
    int N, float* __restrict__ out) {
    __shared__ ull ews[256];
    int wv = threadIdx.x >> 6, lane = threadIdx.x & 63;
    int half = lane >> 5, l5 = lane & 31;
    int slot = l5 >> 3, c4 = l5 & 7;      // slot 0..3; channels 4*c4..4*c4+3
    int n = blockIdx.x * 8 + wv * 2 + half;
    bool act = n < N;
    int nn = act ? n : 0;
    const uint2* h1w = (const uint2*)h1;
    ull* myw = &ews[wv * 64 + half * 32];

    float sd = sdst[nn];
    float wself = ewgt(ssrc[nn] + sd);

    uint2 selfv = h1w[(size_t)nn * 8 + c4];
    float w0 = (slot == 0) ? wself : 0.f;
    float acc0 = w0 * bflo(selfv.x);
    float acc1 = w0 * bfhi(selfv.x);
    float acc2 = w0 * bflo(selfv.y);
    float acc3 = w0 * bfhi(selfv.y);
    float denp = 0.f;

    int beg = act ? rowptr[nn] : 0;
    int end = act ? rowptr[nn + 1] : 0;
    for (int j0 = beg; j0 < end; j0 += 32) {
        int cnt = end - j0; if (cnt > 32) cnt = 32;
        int s = (l5 < cnt) ? csr_src[j0 + l5] : 0;
        bool v = (l5 < cnt) && ((unsigned)s < (unsigned)N);
        int sg = v ? s : 0;
        float wj = v ? ewgt(ssrc[sg] + sd) : 0.f;
        denp += wj;
        myw[l5] = ((ull)__float_as_uint(wj) << 32) | (unsigned)sg;
        // gather: full 16-edge groups (4 slots x 4-deep) then tail
        int k4 = 0;
        int full = cnt & ~15;
        for (; k4 < full; k4 += 16) {
            ull pa = myw[k4 + slot];
            ull pb = myw[k4 + 4 + slot];
            ull pc = myw[k4 + 8 + slot];
            ull pd_ = myw[k4 + 12 + slot];
            float wa = __uint_as_float((unsigned)(pa >> 32));
            float wb = __uint_as_float((unsigned)(pb >> 32));
            float wc = __uint_as_float((unsigned)(pc >> 32));
            float wd = __uint_as_float((unsigned)(pd_ >> 32));
            int sa = (int)(unsigned)(pa & 0xffffffffu);
            int sb = (int)(unsigned)(pb & 0xffffffffu);
            int sc = (int)(unsigned)(pc & 0xffffffffu);
            int sdi = (int)(unsigned)(pd_ & 0xffffffffu);
            uint2 va = h1w[(size_t)sa * 8 + c4];
            uint2 vb = h1w[(size_t)sb * 8 + c4];
            uint2 vc = h1w[(size_t)sc * 8 + c4];
            uint2 vd = h1w[(size_t)sdi * 8 + c4];
            acc0 += wa * bflo(va.x) + wb * bflo(vb.x) + wc * bflo(vc.x) + wd * bflo(vd.x);
            acc1 += wa * bfhi(va.x) + wb * bfhi(vb.x) + wc * bfhi(vc.x) + wd * bfhi(vd.x);
            acc2 += wa * bflo(va.y) + wb * bflo(vb.y) + wc * bflo(vc.y) + wd * bflo(vd.y);
            acc3 += wa * bfhi(va.y) + wb * bfhi(vb.y) + wc * bfhi(vc.y) + wd * bfhi(vd.y);
        }
        for (; k4 < cnt; k4 += 16) {
            int ia = k4 + slot,      ib = k4 + 4 + slot;
            int ic = k4 + 8 + slot,  id = k4 + 12 + slot;
            ull pa = myw[ia < cnt ? ia : 0];
            ull pb = myw[ib < cnt ? ib : 0];
            ull pc = myw[ic < cnt ? ic : 0];
            ull pd_ = myw[id < cnt ? id : 0];
            float wa = (ia < cnt) ? __uint_as_float((unsigned)(pa >> 32)) : 0.f;
            float wb = (ib < cnt) ? __uint_as_float((unsigned)(pb >> 32)) : 0.f;
            float wc = (ic < cnt) ? __uint_as_float((unsigned)(pc >> 32)) : 0.f;
            float wd = (id < cnt) ? __uint_as_float((unsigned)(pd_ >> 32)) : 0.f;
            int sa = (int)(unsigned)(pa & 0xffffffffu);
            int sb = (int)(unsigned)(pb & 0xffffffffu);
            int sc = (int)(unsigned)(pc & 0xffffffffu);
            int sdi = (int)(unsigned)(pd_ & 0xffffffffu);
            uint2 va = h1w[(size_t)sa * 8 + c4];
            uint2 vb = h1w[(size_t)sb * 8 + c4];
            uint2 vc = h1w[(size_t)sc * 8 + c4];
            uint2 vd = h1w[(size_t)sdi * 8 + c4];
            acc0 += wa * bflo(va.x) + wb * bflo(vb.x) + wc * bflo(vc.x) + wd * bflo(vd.x);
            acc1 += wa * bfhi(va.x) + wb * bfhi(vb.x) + wc * bfhi(vc.x) + wd * bfhi(vd.x);
            acc2 += wa * bflo(va.y) + wb * bflo(vb.y) + wc * bflo(vc.y) + wd * bflo(vd.y);
            acc3 += wa * bfhi(va.y) + wb * bfhi(vb.y) + wc * bfhi(vc.y) + wd * bfhi(vd.y);
        }
    }
    // combine the 4 slots (xor 8,16 stay within the 32-lane half)
    acc0 += __shfl_xor(acc0, 8, 64); acc0 += __shfl_xor(acc0, 16, 64);
    acc1 += __shfl_xor(acc1, 8, 64); acc1 += __shfl_xor(acc1, 16, 64);
    acc2 += __shfl_xor(acc2, 8, 64); acc2 += __shfl_xor(acc2, 16, 64);
    acc3 += __shfl_xor(acc3, 8, 64); acc3 += __shfl_xor(acc3, 16, 64);
    float den = denp;
#pragma unroll
    for (int m = 1; m <= 16; m <<= 1) den += __shfl_xor(den, m, 64);
    den += wself;

    uint2 skv = ((const uint2*)skip1)[(size_t)nn * 8 + c4];
    float o0 = sane(acc0 / den + bflo(skv.x));
    float o1 = sane(acc1 / den + bfhi(skv.x));
    float o2 = sane(acc2 / den + bflo(skv.y));
    float o3 = sane(acc3 / den + bfhi(skv.y));
    // log_softmax over the 32 channels held by each 8-lane c4 group
    float m = fmaxf(fmaxf(o0, o1), fmaxf(o2, o3));
#pragma unroll
    for (int k = 1; k <= 4; k <<= 1) m = fmaxf(m, __shfl_xor(m, k, 64));
    float ex = __expf(o0 - m) + __expf(o1 - m) + __expf(o2 - m) + __expf(o3 - m);
#pragma unroll
    for (int k = 1; k <= 4; k <<= 1) ex += __shfl_xor(ex, k, 64);
    float l = __logf(ex);
    float r0 = o0 - m - l, r1 = o1 - m - l, r2 = o2 - m - l, r3 = o3 - m - l;
    if (!isfinite(r0)) r0 = 0.f;
    if (!isfinite(r1)) r1 = 0.f;
    if (!isfinite(r2)) r2 = 0.f;
    if (!isfinite(r3)) r3 = 0.f;
    if (slot == 0 && act) {
        float4 o4; o4.x = r0; o4.y = r1; o4.z = r2; o4.w = r3;
        *(float4*)&out[(size_t)nn * 32 + 4 * c4] = o4;
    }
}

__global__ void k_sentinel(float* __restrict__ out, int n, float val) {
    int i = blockIdx.x * blockDim.x + threadIdx.x;
    if (i < n) out[i] = val;
}

extern "C" void kernel_launch(void* const* d_in, const int* in_sizes, int n_in,
                              void* d_out, int out_size, void* d_ws, size_t ws_size,
                              hipStream_t stream) {
    const void* x  = d_in[0];
    const void* ei = d_in[1];
    float* out = (float*)d_out;

    int N = in_sizes[0] / 128;
    int E = in_sizes[1] / 2;

    int NB  = (N + BR - 1) >> BSHIFT;
    int gch = (E + CHUNK - 1) / CHUNK;
    if (gch < 1) gch = 1;
    bool fast = (N <= (NBMAX << BSHIFT)) && ((size_t)E * 4 <= (size_t)N * 128);

    char* ws = (char*)d_ws;
    size_t off = 0;
    auto alloc = [&](size_t bytes) -> char* {
        char* p = ws + off;
        off += (bytes + 255) & ~(size_t)255;
        return p;
    };
    int*   flags   = (int*)alloc(2 * 4);
    float* Pf      = (float*)alloc(288 * 4);
    __hip_bfloat16* Wg = (__hip_bfloat16*)alloc(20480 * 2);
    int*   rowptr  = (int*)alloc((size_t)(N + 1) * 4);
    int*   cursor  = (int*)alloc((size_t)N * 4);          // -> ssrc overlay after CSR
    float* sdst01  = (float*)alloc((size_t)N * 4);
    int*   bsum    = (int*)alloc(1024 * 4);
    int*   bcount  = (int*)alloc(NBMAX * 4);
    int*   bbase   = (int*)alloc((NBMAX + 1) * 4);
    int*   csr_src = (int*)alloc((size_t)E * 4);
    int*   hist    = (int*)alloc(fast ? (size_t)gch * NB * 4 : 0);
    int*   cb      = (int*)alloc(fast ? (size_t)gch * NB * 4 : 0);
    __hip_bfloat16* h0    = (__hip_bfloat16*)alloc((size_t)N * 64 * 2); // -> h1+skip1; binned overlay
    __hip_bfloat16* skip0 = (__hip_bfloat16*)alloc((size_t)N * 64 * 2); // -> hact in place
    size_t required = off;

    if (ws_size < required) {
        float mb = (float)(double)(ws_size >> 20);
        k_sentinel<<<(out_size + 255) / 256, 256, 0, stream>>>(out, out_size, mb);
        return;
    }

    float* ssrc01 = (float*)cursor;
    __hip_bfloat16* h1    = h0;
    __hip_bfloat16* skip1 = h0 + (size_t)N * 32;

    k_probe<<<1, 256, 0, stream>>>((const unsigned*)x, N * 64, (const unsigned*)ei, flags);
    k_params<<<40, 256, 0, stream>>>(flags, d_in[2], d_in[6], d_in[3], d_in[4],
                                     d_in[5], d_in[7], d_in[8], d_in[12],
                                     d_in[9], d_in[10], d_in[11], d_in[13], Pf, Wg);

    if (fast) {
        unsigned* binned = (unsigned*)h0;
        k_chist<<<gch, 256, 0, stream>>>(ei, flags, E, N, NB, hist);
        k_cscan<<<NB, 1024, 0, stream>>>(hist, gch, NB, cb, bcount);
        k_bscan<<<1, NBMAX, 0, stream>>>(bcount, NB, bbase);
        k_bscatter<<<gch, 256, 0, stream>>>(ei, flags, E, N, NB, bbase, cb, binned);
        k_bbuild<<<NB, 256, 0, stream>>>(binned, bbase, N, NB, rowptr, csr_src);
    } else {
        int B = (N + 1023) / 1024;
        k_zero<<<(N + 255) / 256, 256, 0, stream>>>(cursor, N);
        k_deg<<<(E + 255) / 256, 256, 0, stream>>>(ei, flags, E, N, cursor);
        k_scan1<<<B, 1024, 0, stream>>>(cursor, N, rowptr, bsum);
        k_scan2<<<1, 1024, 0, stream>>>(bsum, B, rowptr, N);
        k_scan3<<<B, 1024, 0, stream>>>(N, rowptr, bsum, cursor);
        k_fill<<<(E + 255) / 256, 256, 0, stream>>>(ei, flags, E, N, cursor, csr_src);
    }

    k_l0<<<(N + 63) / 64, 256, 0, stream>>>(x, flags, Pf, Wg, N,
                                            h0, skip0, ssrc01, sdst01);
    k_l0_agg<<<(N + 7) / 8, 256, 0, stream>>>(rowptr, csr_src, ssrc01, sdst01,
                                              h0, N, skip0);
    k_l1<<<(N + 63) / 64, 256, 0, stream>>>(skip0, Pf, Wg, N,
                                            h1, skip1, ssrc01, sdst01);
    k_l1_agg<<<(N + 7) / 8, 256, 0, stream>>>(rowptr, csr_src, ssrc01, sdst01,
                                              h1, skip1, N, out);
}